// Round 1
// baseline (413.425 us; speedup 1.0000x reference)
//
#include <hip/hip_runtime.h>

#define NN 384
#define EE 12288
#define DD 1280
#define HH 128
#define MMASK 64
#define DISROWS (NN*NN)

typedef short bf16x8 __attribute__((ext_vector_type(8)));
typedef float f32x4  __attribute__((ext_vector_type(4)));

__device__ __forceinline__ unsigned short f2bf(float x){
  unsigned u = __builtin_bit_cast(unsigned, x);
  u += 0x7fffu + ((u >> 16) & 1u);
  return (unsigned short)(u >> 16);
}
__device__ __forceinline__ float bf2f(unsigned short h){
  unsigned u = ((unsigned)h) << 16;
  return __builtin_bit_cast(float, u);
}

// ---------------- small prep kernels ----------------

__global__ void k_feat(const float* __restrict__ lm, const float* __restrict__ nf,
                       float* __restrict__ x0){
  int n = blockIdx.x;
  int d = blockIdx.y*256 + threadIdx.x;
  float v = (d < 1024) ? lm[(n+1)*1024 + d] : nf[n*256 + (d-1024)];
  x0[n*DD + d] = v;
}

__global__ void k_edgew(const float* __restrict__ ef, float* __restrict__ ew){
  int e = blockIdx.x*256 + threadIdx.x;
  float f = ef[e];
  ew[e] = 1.0f/(f*f + 1e-6f);
}

__global__ void k_zero(int* __restrict__ cnt){
  int i = blockIdx.x*256 + threadIdx.x;
  if (i < NN) cnt[i] = 0;
}

__global__ void k_count(const int* __restrict__ dst, int* __restrict__ cnt){
  int e = blockIdx.x*256 + threadIdx.x;
  atomicAdd(&cnt[dst[e]], 1);
}

__global__ void k_scan(const int* __restrict__ cnt, int* __restrict__ offs,
                       int* __restrict__ pos){
  __shared__ int s[512];
  int t = threadIdx.x;
  int c = (t < NN) ? cnt[t] : 0;
  s[t] = c;
  __syncthreads();
  for (int off = 1; off < 512; off <<= 1){
    int v = (t >= off) ? s[t-off] : 0;
    __syncthreads();
    s[t] += v;
    __syncthreads();
  }
  if (t < NN){
    int excl = s[t] - c;
    offs[t] = excl;
    pos[t]  = excl;
  }
  if (t == NN) offs[NN] = EE;
}

__global__ void k_place(const int* __restrict__ dst, int* __restrict__ pos,
                        int* __restrict__ sorted){
  int e = blockIdx.x*256 + threadIdx.x;
  int p = atomicAdd(&pos[dst[e]], 1);
  sorted[p] = e;
}

// y[v] = x[v] + sum_{e: dst==v} ew[e] * x[src[e]]
__global__ void k_agg(const float* __restrict__ X, const float* __restrict__ ew,
                      const int* __restrict__ src, const int* __restrict__ offs,
                      const int* __restrict__ sorted, float* __restrict__ Y){
  int v = blockIdx.x;
  int d = blockIdx.y*256 + threadIdx.x;
  float acc = X[v*DD + d];
  int b = offs[v], e = offs[v+1];
  for (int k = b; k < e; ++k){
    int eid = sorted[k];
    acc += ew[eid] * X[src[eid]*DD + d];
  }
  Y[v*DD + d] = acc;
}

// transpose W[R][C] -> Thi/Tlo[C][R] as bf16 hi (+ optional lo residual)
__global__ void k_tsplit(const float* __restrict__ W, short* __restrict__ Thi,
                         short* __restrict__ Tlo, int R, int C){
  __shared__ float tile[64][65];
  int rb = blockIdx.y*64, cb = blockIdx.x*64;
  int t = threadIdx.x;
  int r  = t >> 2;
  int cs = (t & 3) * 16;
  const float* sp = W + (long)(rb + r)*C + cb + cs;
  #pragma unroll
  for (int i = 0; i < 16; i += 4){
    f32x4 v = *(const f32x4*)(sp + i);
    tile[r][cs+i+0] = v[0]; tile[r][cs+i+1] = v[1];
    tile[r][cs+i+2] = v[2]; tile[r][cs+i+3] = v[3];
  }
  __syncthreads();
  int cp = t >> 2;          // local col of W = row of T
  int rs = (t & 3) * 16;    // local row of W = col of T
  bf16x8 vh0, vh1, vl0, vl1;
  #pragma unroll
  for (int i = 0; i < 8; ++i){
    float f = tile[rs+i][cp];
    unsigned short h = f2bf(f);
    vh0[i] = (short)h; vl0[i] = (short)f2bf(f - bf2f(h));
  }
  #pragma unroll
  for (int i = 0; i < 8; ++i){
    float f = tile[rs+8+i][cp];
    unsigned short h = f2bf(f);
    vh1[i] = (short)h; vl1[i] = (short)f2bf(f - bf2f(h));
  }
  long ob = (long)(cb + cp)*R + rb + rs;
  *(bf16x8*)&Thi[ob]   = vh0;
  *(bf16x8*)&Thi[ob+8] = vh1;
  if (Tlo){
    *(bf16x8*)&Tlo[ob]   = vl0;
    *(bf16x8*)&Tlo[ob+8] = vl1;
  }
}

__global__ void k_wd2t(const float* __restrict__ Wd2, short* __restrict__ W2t){
  int t = threadIdx.x;
  for (int i = t; i < 32*HH; i += 256){
    int c = i >> 7, h = i & 127;
    float v = (c < 30) ? Wd2[h*30 + c] : 0.f;
    W2t[i] = (short)f2bf(v);
  }
}

// ---------------- GIN GEMM: Out = Y @ W + bias (+resid), split-bf16 ----------------
// Wt layout: [1280 out][1280 in] bf16 hi/lo. Tile 128x128, BK=32, 4 waves.
__launch_bounds__(256, 2)
__global__ void k_gin_gemm(const float* __restrict__ Y, const short* __restrict__ Whi,
                           const short* __restrict__ Wlo, const float* __restrict__ bias,
                           const float* __restrict__ resid, float* __restrict__ Out){
  __shared__ __align__(16) short Ahi[128*40], Alo[128*40], Bhi[128*40], Blo[128*40];
  int m0 = blockIdx.x*128;
  int n0 = blockIdx.y*128;
  int t = threadIdx.x, w = t >> 6, lane = t & 63;
  int l15 = lane & 15, l4 = lane >> 4;
  f32x4 acc[2][8];
  #pragma unroll
  for (int m = 0; m < 2; ++m)
    #pragma unroll
    for (int n = 0; n < 8; ++n) acc[m][n] = (f32x4){0.f,0.f,0.f,0.f};

  int row = t >> 1, half = t & 1;
  const float* ap = Y + (long)(m0+row)*DD + half*16;
  const short* bph = Whi + (long)(n0+row)*DD + half*16;
  const short* bpl = Wlo + (long)(n0+row)*DD + half*16;

  for (int kk = 0; kk < 40; ++kk){
    int d0 = kk*32;
    __syncthreads();
    // stage A (fp32 -> hi/lo bf16)
    #pragma unroll
    for (int g = 0; g < 2; ++g){
      f32x4 v0 = *(const f32x4*)(ap + d0 + g*8);
      f32x4 v1 = *(const f32x4*)(ap + d0 + g*8 + 4);
      bf16x8 vh, vl;
      #pragma unroll
      for (int q = 0; q < 4; ++q){
        unsigned short h0 = f2bf(v0[q]);
        vh[q]   = (short)h0; vl[q]   = (short)f2bf(v0[q] - bf2f(h0));
        unsigned short h1 = f2bf(v1[q]);
        vh[4+q] = (short)h1; vl[4+q] = (short)f2bf(v1[q] - bf2f(h1));
      }
      *(bf16x8*)&Ahi[row*40 + half*16 + g*8] = vh;
      *(bf16x8*)&Alo[row*40 + half*16 + g*8] = vl;
    }
    // stage B (already bf16)
    *(bf16x8*)&Bhi[row*40 + half*16]     = *(const bf16x8*)(bph + d0);
    *(bf16x8*)&Bhi[row*40 + half*16 + 8] = *(const bf16x8*)(bph + d0 + 8);
    *(bf16x8*)&Blo[row*40 + half*16]     = *(const bf16x8*)(bpl + d0);
    *(bf16x8*)&Blo[row*40 + half*16 + 8] = *(const bf16x8*)(bpl + d0 + 8);
    __syncthreads();

    bf16x8 ah[2], al[2];
    #pragma unroll
    for (int m = 0; m < 2; ++m){
      int rr = w*32 + m*16 + l15;
      ah[m] = *(const bf16x8*)&Ahi[rr*40 + l4*8];
      al[m] = *(const bf16x8*)&Alo[rr*40 + l4*8];
    }
    #pragma unroll
    for (int n = 0; n < 8; ++n){
      int rr = n*16 + l15;
      bf16x8 bh = *(const bf16x8*)&Bhi[rr*40 + l4*8];
      bf16x8 bl = *(const bf16x8*)&Blo[rr*40 + l4*8];
      #pragma unroll
      for (int m = 0; m < 2; ++m){
        acc[m][n] = __builtin_amdgcn_mfma_f32_16x16x32_bf16(ah[m], bh, acc[m][n], 0,0,0);
        acc[m][n] = __builtin_amdgcn_mfma_f32_16x16x32_bf16(ah[m], bl, acc[m][n], 0,0,0);
        acc[m][n] = __builtin_amdgcn_mfma_f32_16x16x32_bf16(al[m], bh, acc[m][n], 0,0,0);
      }
    }
  }
  #pragma unroll
  for (int m = 0; m < 2; ++m){
    #pragma unroll
    for (int n = 0; n < 8; ++n){
      int gr0 = m0 + w*32 + m*16 + l4*4;
      int gc  = n0 + n*16 + l15;
      float bv = bias[gc];
      #pragma unroll
      for (int r = 0; r < 4; ++r){
        float o = acc[m][n][r] + bv;
        if (resid) o += resid[(long)(gr0+r)*DD + gc];
        Out[(long)(gr0+r)*DD + gc] = o;
      }
    }
  }
}

// ---------------- fused dis MLP ----------------
// Block: 16 i x 16 j = 256 pairs, full H=128. 4 waves, wave w: ii in [4w,4w+4).
__launch_bounds__(256, 2)
__global__ void k_dis(const float* __restrict__ X, const short* __restrict__ W1t,
                      const float* __restrict__ bd1, const short* __restrict__ W2t,
                      const float* __restrict__ bd2, float* __restrict__ out){
  __shared__ __align__(16) short smem[256*136];   // 69632 B; first 128*40 = B tile
  int t = threadIdx.x, w = t >> 6, lane = t & 63;
  int l15 = lane & 15, l4 = lane >> 4;
  int i0 = blockIdx.y*16, j0 = blockIdx.x*16;

  f32x4 acc[4][8];
  #pragma unroll
  for (int m = 0; m < 4; ++m)
    #pragma unroll
    for (int n = 0; n < 8; ++n) acc[m][n] = (f32x4){0.f,0.f,0.f,0.f};

  float b1v[8];
  #pragma unroll
  for (int n = 0; n < 8; ++n) b1v[n] = bd1[n*16 + l15];

  int srow = t >> 1, shalf = t & 1;
  const short* wsrc = W1t + (long)srow*DD + shalf*16;
  const float* xj_base = X + (long)(j0 + l15)*DD + l4*8;

  for (int kk = 0; kk < 40; ++kk){
    int d0 = kk*32;
    __syncthreads();
    *(bf16x8*)&smem[srow*40 + shalf*16]     = *(const bf16x8*)(wsrc + d0);
    *(bf16x8*)&smem[srow*40 + shalf*16 + 8] = *(const bf16x8*)(wsrc + d0 + 8);
    __syncthreads();

    f32x4 xj0 = *(const f32x4*)(xj_base + d0);
    f32x4 xj1 = *(const f32x4*)(xj_base + d0 + 4);
    bf16x8 a[4];
    #pragma unroll
    for (int m = 0; m < 4; ++m){
      const float* xip = X + (long)(i0 + w*4 + m)*DD + d0 + l4*8;
      f32x4 xi0 = *(const f32x4*)xip;
      f32x4 xi1 = *(const f32x4*)(xip + 4);
      bf16x8 av;
      #pragma unroll
      for (int q = 0; q < 4; ++q){
        float dl = xj0[q] - xi0[q];
        av[q] = (short)f2bf(dl*dl);
      }
      #pragma unroll
      for (int q = 0; q < 4; ++q){
        float dl = xj1[q] - xi1[q];
        av[4+q] = (short)f2bf(dl*dl);
      }
      a[m] = av;
    }
    bf16x8 b[8];
    #pragma unroll
    for (int n = 0; n < 8; ++n)
      b[n] = *(const bf16x8*)&smem[(n*16 + l15)*40 + l4*8];
    #pragma unroll
    for (int m = 0; m < 4; ++m)
      #pragma unroll
      for (int n = 0; n < 8; ++n)
        acc[m][n] = __builtin_amdgcn_mfma_f32_16x16x32_bf16(a[m], b[n], acc[m][n], 0,0,0);
  }

  __syncthreads();   // all B reads done before aliasing smem as t-buffer
  // t = relu(acc + bd1) -> bf16 into t_lds[256][136]
  #pragma unroll
  for (int m = 0; m < 4; ++m){
    int pb = (w*4 + m)*16 + l4*4;
    #pragma unroll
    for (int n = 0; n < 8; ++n){
      int h = n*16 + l15;
      #pragma unroll
      for (int r = 0; r < 4; ++r){
        float v = acc[m][n][r] + b1v[n];
        v = v > 0.f ? v : 0.f;
        smem[(pb + r)*136 + h] = (short)f2bf(v);
      }
    }
  }
  __syncthreads();

  // layer 2: [64 pairs x 128h] @ [128h x 32c]
  f32x4 acc2[4][2];
  #pragma unroll
  for (int m = 0; m < 4; ++m)
    #pragma unroll
    for (int n = 0; n < 2; ++n) acc2[m][n] = (f32x4){0.f,0.f,0.f,0.f};

  #pragma unroll
  for (int hs = 0; hs < 4; ++hs){
    bf16x8 a2[4];
    #pragma unroll
    for (int m = 0; m < 4; ++m)
      a2[m] = *(const bf16x8*)&smem[(w*64 + m*16 + l15)*136 + hs*32 + l4*8];
    bf16x8 b2[2];
    #pragma unroll
    for (int n = 0; n < 2; ++n)
      b2[n] = *(const bf16x8*)&W2t[(n*16 + l15)*HH + hs*32 + l4*8];
    #pragma unroll
    for (int m = 0; m < 4; ++m)
      #pragma unroll
      for (int n = 0; n < 2; ++n)
        acc2[m][n] = __builtin_amdgcn_mfma_f32_16x16x32_bf16(a2[m], b2[n], acc2[m][n], 0,0,0);
  }

  #pragma unroll
  for (int m = 0; m < 4; ++m){
    int pl0 = w*64 + m*16 + l4*4;
    #pragma unroll
    for (int n = 0; n < 2; ++n){
      int c = n*16 + l15;
      if (c < 30){
        float b2v = bd2[c];
        #pragma unroll
        for (int r = 0; r < 4; ++r){
          int p = pl0 + r;
          int gi = i0 + (p >> 4), gj = j0 + (p & 15);
          out[((long)gi*NN + gj)*30 + c] = acc2[m][n][r] + b2v;
        }
      }
    }
  }
}

// ---------------- mask head ----------------
__global__ void k_mask(const float* __restrict__ X, const int* __restrict__ midx,
                       const float* __restrict__ Wm1, const float* __restrict__ bm1,
                       const float* __restrict__ Wm2, const float* __restrict__ bm2,
                       float* __restrict__ out){
  __shared__ float tl[HH];
  int m = blockIdx.x, t = threadIdx.x;   // 128 threads
  const float* x = X + (long)midx[m]*DD;
  float a0 = 0.f, a1 = 0.f, a2 = 0.f, a3 = 0.f;
  for (int d = 0; d < DD; d += 4){
    a0 += x[d]   * Wm1[(d)*HH + t];
    a1 += x[d+1] * Wm1[(d+1)*HH + t];
    a2 += x[d+2] * Wm1[(d+2)*HH + t];
    a3 += x[d+3] * Wm1[(d+3)*HH + t];
  }
  float v = a0 + a1 + a2 + a3 + bm1[t];
  tl[t] = v > 0.f ? v : 0.f;
  __syncthreads();
  if (t < 2){
    float s = bm2[t];
    for (int h = 0; h < HH; ++h) s += tl[h]*Wm2[h*2 + t];
    out[(long)DISROWS*30 + m*2 + t] = tanhf(s);
  }
}

// ---------------- launch ----------------
extern "C" void kernel_launch(void* const* d_in, const int* in_sizes, int n_in,
                              void* d_out, int out_size, void* d_ws, size_t ws_size,
                              hipStream_t stream){
  const float* lm   = (const float*)d_in[0];
  const float* nf   = (const float*)d_in[1];
  const float* ef   = (const float*)d_in[2];
  const int*   src  = (const int*)d_in[3];
  const int*   dst  = (const int*)d_in[4];
  const int*   midx = (const int*)d_in[5];
  const float* Wg0  = (const float*)d_in[6];
  const float* bg0  = (const float*)d_in[7];
  const float* Wg1  = (const float*)d_in[8];
  const float* bg1  = (const float*)d_in[9];
  const float* Wd1  = (const float*)d_in[10];
  const float* bd1  = (const float*)d_in[11];
  const float* Wd2  = (const float*)d_in[12];
  const float* bd2  = (const float*)d_in[13];
  const float* Wm1  = (const float*)d_in[14];
  const float* bm1  = (const float*)d_in[15];
  const float* Wm2  = (const float*)d_in[16];
  const float* bm2  = (const float*)d_in[17];
  float* dis = (float*)d_out;

  char* ws = (char*)d_ws;
  size_t off = 0;
  auto alloc = [&](size_t bytes)->void*{
    void* p = ws + off; off += (bytes + 255) & ~(size_t)255; return p;
  };
  float* x0   = (float*)alloc((size_t)NN*DD*4);
  float* yb   = (float*)alloc((size_t)NN*DD*4);
  float* hb   = (float*)alloc((size_t)NN*DD*4);
  float* ew   = (float*)alloc((size_t)EE*4);
  int*   cnt  = (int*)alloc(NN*4);
  int*   offs = (int*)alloc((NN+1)*4);
  int*   pos  = (int*)alloc(NN*4);
  int*   sorted = (int*)alloc(EE*4);
  short* Wt0h = (short*)alloc((size_t)DD*DD*2);
  short* Wt0l = (short*)alloc((size_t)DD*DD*2);
  short* Wt1h = (short*)alloc((size_t)DD*DD*2);
  short* Wt1l = (short*)alloc((size_t)DD*DD*2);
  short* W1t  = (short*)alloc((size_t)HH*DD*2);
  short* W2t  = (short*)alloc((size_t)32*HH*2);

  k_feat <<<dim3(384,5),256,0,stream>>>(lm, nf, x0);
  k_edgew<<<48,256,0,stream>>>(ef, ew);
  k_zero <<<2,256,0,stream>>>(cnt);
  k_count<<<48,256,0,stream>>>(dst, cnt);
  k_scan <<<1,512,0,stream>>>(cnt, offs, pos);
  k_place<<<48,256,0,stream>>>(dst, pos, sorted);

  k_tsplit<<<dim3(20,20),256,0,stream>>>(Wg0, Wt0h, Wt0l, DD, DD);
  k_tsplit<<<dim3(20,20),256,0,stream>>>(Wg1, Wt1h, Wt1l, DD, DD);
  k_tsplit<<<dim3(2,20),256,0,stream>>>(Wd1, W1t, nullptr, DD, HH);
  k_wd2t<<<1,256,0,stream>>>(Wd2, W2t);

  k_agg<<<dim3(384,5),256,0,stream>>>(x0, ew, src, offs, sorted, yb);
  k_gin_gemm<<<dim3(3,10),256,0,stream>>>(yb, Wt0h, Wt0l, bg0, nullptr, hb);
  k_agg<<<dim3(384,5),256,0,stream>>>(hb, ew, src, offs, sorted, yb);
  k_gin_gemm<<<dim3(3,10),256,0,stream>>>(yb, Wt1h, Wt1l, bg1, x0, hb);

  k_dis<<<dim3(24,24),256,0,stream>>>(hb, W1t, bd1, W2t, bd2, dis);
  k_mask<<<64,128,0,stream>>>(hb, midx, Wm1, bm1, Wm2, bm2, dis);
}

// Round 2
// 289.763 us; speedup vs baseline: 1.4268x; 1.4268x over previous
//
#include <hip/hip_runtime.h>
#include <hip/hip_bf16.h>

#define NN 384
#define EE 12288
#define DD 1280
#define HH 128
#define DISROWS (NN*NN)

typedef short bf16x8 __attribute__((ext_vector_type(8)));
typedef float f32x4  __attribute__((ext_vector_type(4)));

__device__ __forceinline__ unsigned short f2bf(float x){
  unsigned u = __builtin_bit_cast(unsigned, x);
  u += 0x7fffu + ((u >> 16) & 1u);
  return (unsigned short)(u >> 16);
}
__device__ __forceinline__ float bf2f(unsigned short h){
  unsigned u = ((unsigned)h) << 16;
  return __builtin_bit_cast(float, u);
}
__device__ __forceinline__ short f2bf_fast(float x){
  return (short)__bfloat16_as_ushort(__float2bfloat16(x));
}

// ---------------- prep ----------------

__global__ void k_feat(const float* __restrict__ lm, const float* __restrict__ nf,
                       float* __restrict__ x0){
  int n = blockIdx.x;
  int d = blockIdx.y*256 + threadIdx.x;
  float v = (d < 1024) ? lm[(n+1)*1024 + d] : nf[n*256 + (d-1024)];
  x0[n*DD + d] = v;
}

// single-block: edge weights + CSR(count/scan/place)
__global__ void k_graph(const int* __restrict__ dst, const float* __restrict__ ef,
                        int* __restrict__ offs, int* __restrict__ sorted,
                        float* __restrict__ ew){
  __shared__ int cnt[512];
  __shared__ int base[NN];
  const int t = threadIdx.x;  // 1024
  if (t < 512) cnt[t] = 0;
  __syncthreads();
  for (int e = t; e < EE; e += 1024){
    atomicAdd(&cnt[dst[e]], 1);
    float f = ef[e];
    ew[e] = 1.0f/(f*f + 1e-6f);
  }
  __syncthreads();
  for (int off = 1; off < 512; off <<= 1){
    int v = 0;
    if (t < 512 && t >= off) v = cnt[t - off];
    __syncthreads();
    if (t < 512) cnt[t] += v;
    __syncthreads();
  }
  if (t < NN){
    int excl = t ? cnt[t-1] : 0;
    offs[t] = excl;
    base[t] = excl;
  }
  if (t == 0) offs[NN] = EE;
  __syncthreads();
  for (int e = t; e < EE; e += 1024){
    int p = atomicAdd(&base[dst[e]], 1);
    sorted[p] = e;
  }
}

// y[v] = x[v] + sum_{e: dst==v} ew[e] * x[src[e]]
__global__ void k_agg(const float* __restrict__ X, const float* __restrict__ ew,
                      const int* __restrict__ src, const int* __restrict__ offs,
                      const int* __restrict__ sorted, float* __restrict__ Y){
  __shared__ int   s_off[160];
  __shared__ float s_w[160];
  const int v = blockIdx.x;
  const int d = blockIdx.y*256 + threadIdx.x;
  const int t = threadIdx.x;
  float acc = X[(long)v*DD + d];
  const int b = offs[v], e = offs[v+1];
  for (int c0 = b; c0 < e; c0 += 160){
    int n = e - c0; if (n > 160) n = 160;
    __syncthreads();
    if (t < n){
      int eid = sorted[c0 + t];
      s_off[t] = src[eid]*DD;
      s_w[t]   = ew[eid];
    }
    __syncthreads();
    int k = 0;
    for (; k + 4 <= n; k += 4){
      acc += s_w[k]  *X[s_off[k]   + d];
      acc += s_w[k+1]*X[s_off[k+1] + d];
      acc += s_w[k+2]*X[s_off[k+2] + d];
      acc += s_w[k+3]*X[s_off[k+3] + d];
    }
    for (; k < n; ++k) acc += s_w[k]*X[s_off[k] + d];
  }
  Y[(long)v*DD + d] = acc;
}

// transpose W[R][C] -> Thi/Tlo[C][R] as bf16 hi (+ optional lo residual)
__global__ void k_tsplit(const float* __restrict__ W, short* __restrict__ Thi,
                         short* __restrict__ Tlo, int R, int C){
  __shared__ float tile[64][65];
  int rb = blockIdx.y*64, cb = blockIdx.x*64;
  int t = threadIdx.x;
  int r  = t >> 2;
  int cs = (t & 3) * 16;
  const float* sp = W + (long)(rb + r)*C + cb + cs;
  #pragma unroll
  for (int i = 0; i < 16; i += 4){
    f32x4 v = *(const f32x4*)(sp + i);
    tile[r][cs+i+0] = v[0]; tile[r][cs+i+1] = v[1];
    tile[r][cs+i+2] = v[2]; tile[r][cs+i+3] = v[3];
  }
  __syncthreads();
  int cp = t >> 2;
  int rs = (t & 3) * 16;
  bf16x8 vh0, vh1, vl0, vl1;
  #pragma unroll
  for (int i = 0; i < 8; ++i){
    float f = tile[rs+i][cp];
    unsigned short h = f2bf(f);
    vh0[i] = (short)h; vl0[i] = (short)f2bf(f - bf2f(h));
  }
  #pragma unroll
  for (int i = 0; i < 8; ++i){
    float f = tile[rs+8+i][cp];
    unsigned short h = f2bf(f);
    vh1[i] = (short)h; vl1[i] = (short)f2bf(f - bf2f(h));
  }
  long ob = (long)(cb + cp)*R + rb + rs;
  *(bf16x8*)&Thi[ob]   = vh0;
  *(bf16x8*)&Thi[ob+8] = vh1;
  if (Tlo){
    *(bf16x8*)&Tlo[ob]   = vl0;
    *(bf16x8*)&Tlo[ob+8] = vl1;
  }
}

__global__ void k_wd2t(const float* __restrict__ Wd2, short* __restrict__ W2t){
  int t = threadIdx.x;
  for (int i = t; i < 32*HH; i += 256){
    int c = i >> 7, h = i & 127;
    float v = (c < 30) ? Wd2[h*30 + c] : 0.f;
    W2t[i] = (short)f2bf(v);
  }
}

// ---------------- GIN GEMM, split-K=4: P[z] = Y @ W (K-chunk z), split-bf16 ----------------
__launch_bounds__(256, 2)
__global__ void k_gin_gemm(const float* __restrict__ Y, const short* __restrict__ Whi,
                           const short* __restrict__ Wlo, float* __restrict__ P){
  __shared__ __align__(16) short Ahi[128*40], Alo[128*40], Bhi[128*40], Blo[128*40];
  const int m0 = blockIdx.x*128;
  const int n0 = blockIdx.y*128;
  const int kbase = blockIdx.z*320;
  const int t = threadIdx.x, w = t >> 6, lane = t & 63;
  const int l15 = lane & 15, l4 = lane >> 4;
  f32x4 acc[2][8];
  #pragma unroll
  for (int m = 0; m < 2; ++m)
    #pragma unroll
    for (int n = 0; n < 8; ++n) acc[m][n] = (f32x4){0.f,0.f,0.f,0.f};

  const int row = t >> 1, half = t & 1;
  const float* ap  = Y   + (long)(m0+row)*DD + half*16;
  const short* bph = Whi + (long)(n0+row)*DD + half*16;
  const short* bpl = Wlo + (long)(n0+row)*DD + half*16;

  for (int kk = 0; kk < 10; ++kk){
    int d0 = kbase + kk*32;
    __syncthreads();
    #pragma unroll
    for (int g = 0; g < 2; ++g){
      f32x4 v0 = *(const f32x4*)(ap + d0 + g*8);
      f32x4 v1 = *(const f32x4*)(ap + d0 + g*8 + 4);
      bf16x8 vh, vl;
      #pragma unroll
      for (int q = 0; q < 4; ++q){
        unsigned short h0 = f2bf(v0[q]);
        vh[q]   = (short)h0; vl[q]   = (short)f2bf(v0[q] - bf2f(h0));
        unsigned short h1 = f2bf(v1[q]);
        vh[4+q] = (short)h1; vl[4+q] = (short)f2bf(v1[q] - bf2f(h1));
      }
      *(bf16x8*)&Ahi[row*40 + half*16 + g*8] = vh;
      *(bf16x8*)&Alo[row*40 + half*16 + g*8] = vl;
    }
    *(bf16x8*)&Bhi[row*40 + half*16]     = *(const bf16x8*)(bph + d0);
    *(bf16x8*)&Bhi[row*40 + half*16 + 8] = *(const bf16x8*)(bph + d0 + 8);
    *(bf16x8*)&Blo[row*40 + half*16]     = *(const bf16x8*)(bpl + d0);
    *(bf16x8*)&Blo[row*40 + half*16 + 8] = *(const bf16x8*)(bpl + d0 + 8);
    __syncthreads();

    bf16x8 ah[2], al[2];
    #pragma unroll
    for (int m = 0; m < 2; ++m){
      int rr = w*32 + m*16 + l15;
      ah[m] = *(const bf16x8*)&Ahi[rr*40 + l4*8];
      al[m] = *(const bf16x8*)&Alo[rr*40 + l4*8];
    }
    #pragma unroll
    for (int n = 0; n < 8; ++n){
      int rr = n*16 + l15;
      bf16x8 bh = *(const bf16x8*)&Bhi[rr*40 + l4*8];
      bf16x8 bl = *(const bf16x8*)&Blo[rr*40 + l4*8];
      #pragma unroll
      for (int m = 0; m < 2; ++m){
        acc[m][n] = __builtin_amdgcn_mfma_f32_16x16x32_bf16(ah[m], bh, acc[m][n], 0,0,0);
        acc[m][n] = __builtin_amdgcn_mfma_f32_16x16x32_bf16(ah[m], bl, acc[m][n], 0,0,0);
        acc[m][n] = __builtin_amdgcn_mfma_f32_16x16x32_bf16(al[m], bh, acc[m][n], 0,0,0);
      }
    }
  }
  float* Pz = P + (long)blockIdx.z*NN*DD;
  #pragma unroll
  for (int m = 0; m < 2; ++m){
    #pragma unroll
    for (int n = 0; n < 8; ++n){
      int gr0 = m0 + w*32 + m*16 + l4*4;
      int gc  = n0 + n*16 + l15;
      #pragma unroll
      for (int r = 0; r < 4; ++r)
        Pz[(long)(gr0+r)*DD + gc] = acc[m][n][r];
    }
  }
}

__global__ void k_gin_reduce(const float* __restrict__ P, const float* __restrict__ bias,
                             const float* __restrict__ resid, float* __restrict__ Out){
  const int i = blockIdx.x*256 + threadIdx.x;   // over 122880 f32x4
  const int col = (i*4) % DD;
  const f32x4* P4 = (const f32x4*)P;
  f32x4 s = P4[i];
  s += P4[i + 122880];
  s += P4[i + 2*122880];
  s += P4[i + 3*122880];
  s += *(const f32x4*)(bias + col);
  if (resid) s += ((const f32x4*)resid)[i];
  ((f32x4*)Out)[i] = s;
}

// ---------------- fused dis MLP ----------------
// 16i x 16j pairs, H=128. dbuf W-tile (1 barrier/K-step), layer-2 in 2 chunks.
__launch_bounds__(256, 2)
__global__ void k_dis(const float* __restrict__ X, const short* __restrict__ W1t,
                      const float* __restrict__ bd1, const short* __restrict__ W2t,
                      const float* __restrict__ bd2, float* __restrict__ out){
  __shared__ __align__(16) short smem[17408];   // 34816 B (W dbuf 2x5120; t-chunk 128x136)
  const int t = threadIdx.x, w = t >> 6, lane = t & 63;
  const int l15 = lane & 15, l4 = lane >> 4;
  const int i0 = blockIdx.y*16, j0 = blockIdx.x*16;

  f32x4 acc[4][8];
  #pragma unroll
  for (int m = 0; m < 4; ++m)
    #pragma unroll
    for (int n = 0; n < 8; ++n) acc[m][n] = (f32x4){0.f,0.f,0.f,0.f};

  float b1v[8];
  #pragma unroll
  for (int n = 0; n < 8; ++n) b1v[n] = bd1[n*16 + l15];

  const int srow = t >> 1, shalf = t & 1;
  const int woff = srow*40 + shalf*16;
  const short* wsrc = W1t + (long)srow*DD + shalf*16;
  const float* xj_base = X + (long)(j0 + l15)*DD + l4*8;
  const float* xi_base = X + (long)(i0 + w*4)*DD + l4*8;

  {
    bf16x8 wa = *(const bf16x8*)(wsrc);
    bf16x8 wb = *(const bf16x8*)(wsrc + 8);
    *(bf16x8*)&smem[woff]     = wa;
    *(bf16x8*)&smem[woff + 8] = wb;
  }
  f32x4 xja = *(const f32x4*)(xj_base);
  f32x4 xjb = *(const f32x4*)(xj_base + 4);
  __syncthreads();

  for (int kk = 0; kk < 40; ++kk){
    const int cur = (kk & 1) ? 5120 : 0;
    const int nxt = 5120 - cur;
    const int d0 = kk*32, d1 = d0 + 32;
    bf16x8 nwa, nwb; f32x4 nxja, nxjb;
    if (kk < 39){
      nwa  = *(const bf16x8*)(wsrc + d1);
      nwb  = *(const bf16x8*)(wsrc + d1 + 8);
      nxja = *(const f32x4*)(xj_base + d1);
      nxjb = *(const f32x4*)(xj_base + d1 + 4);
    }
    bf16x8 a[4];
    #pragma unroll
    for (int m = 0; m < 4; ++m){
      const float* xip = xi_base + (long)m*DD + d0;
      f32x4 xi0 = *(const f32x4*)xip;
      f32x4 xi1 = *(const f32x4*)(xip + 4);
      bf16x8 av;
      #pragma unroll
      for (int q = 0; q < 4; ++q){ float dl = xja[q]-xi0[q]; av[q]   = f2bf_fast(dl*dl); }
      #pragma unroll
      for (int q = 0; q < 4; ++q){ float dl = xjb[q]-xi1[q]; av[4+q] = f2bf_fast(dl*dl); }
      a[m] = av;
    }
    bf16x8 b[8];
    #pragma unroll
    for (int n = 0; n < 8; ++n)
      b[n] = *(const bf16x8*)&smem[cur + (n*16 + l15)*40 + l4*8];
    #pragma unroll
    for (int m = 0; m < 4; ++m)
      #pragma unroll
      for (int n = 0; n < 8; ++n)
        acc[m][n] = __builtin_amdgcn_mfma_f32_16x16x32_bf16(a[m], b[n], acc[m][n], 0,0,0);
    if (kk < 39){
      *(bf16x8*)&smem[nxt + woff]     = nwa;
      *(bf16x8*)&smem[nxt + woff + 8] = nwb;
      xja = nxja; xjb = nxjb;
    }
    __syncthreads();
  }

  // layer 2, two chunks of 128 pairs (waves 0,1 own chunk0 rows; 2,3 own chunk1)
  #pragma unroll
  for (int c = 0; c < 2; ++c){
    if ((w >> 1) == c){
      #pragma unroll
      for (int m = 0; m < 4; ++m){
        int lp0 = ((w & 1)*4 + m)*16 + l4*4;
        #pragma unroll
        for (int n = 0; n < 8; ++n){
          int h = n*16 + l15;
          #pragma unroll
          for (int r = 0; r < 4; ++r){
            float v = acc[m][n][r] + b1v[n];
            v = v > 0.f ? v : 0.f;
            smem[(lp0 + r)*136 + h] = f2bf_fast(v);
          }
        }
      }
    }
    __syncthreads();

    f32x4 acc2[2][2];
    #pragma unroll
    for (int mm = 0; mm < 2; ++mm)
      #pragma unroll
      for (int nn = 0; nn < 2; ++nn) acc2[mm][nn] = (f32x4){0.f,0.f,0.f,0.f};
    #pragma unroll
    for (int hs = 0; hs < 4; ++hs){
      bf16x8 a2[2], b2[2];
      #pragma unroll
      for (int mm = 0; mm < 2; ++mm)
        a2[mm] = *(const bf16x8*)&smem[(w*32 + mm*16 + l15)*136 + hs*32 + l4*8];
      #pragma unroll
      for (int nn = 0; nn < 2; ++nn)
        b2[nn] = *(const bf16x8*)&W2t[(nn*16 + l15)*HH + hs*32 + l4*8];
      #pragma unroll
      for (int mm = 0; mm < 2; ++mm)
        #pragma unroll
        for (int nn = 0; nn < 2; ++nn)
          acc2[mm][nn] = __builtin_amdgcn_mfma_f32_16x16x32_bf16(a2[mm], b2[nn], acc2[mm][nn], 0,0,0);
    }
    #pragma unroll
    for (int mm = 0; mm < 2; ++mm){
      #pragma unroll
      for (int nn = 0; nn < 2; ++nn){
        int cc = nn*16 + l15;
        if (cc < 30){
          float b2v = bd2[cc];
          #pragma unroll
          for (int r = 0; r < 4; ++r){
            int gp = c*128 + w*32 + mm*16 + l4*4 + r;
            int gi = i0 + (gp >> 4), gj = j0 + (gp & 15);
            out[((long)gi*NN + gj)*30 + cc] = acc2[mm][nn][r] + b2v;
          }
        }
      }
    }
    if (c == 0) __syncthreads();
  }
}

// ---------------- mask head ----------------
__global__ void k_mask(const float* __restrict__ X, const int* __restrict__ midx,
                       const float* __restrict__ Wm1, const float* __restrict__ bm1,
                       const float* __restrict__ Wm2, const float* __restrict__ bm2,
                       float* __restrict__ out){
  __shared__ float tl[HH];
  int m = blockIdx.x, t = threadIdx.x;   // 128 threads
  const float* x = X + (long)midx[m]*DD;
  float a0 = 0.f, a1 = 0.f, a2 = 0.f, a3 = 0.f;
  for (int d = 0; d < DD; d += 4){
    a0 += x[d]   * Wm1[(d)*HH + t];
    a1 += x[d+1] * Wm1[(d+1)*HH + t];
    a2 += x[d+2] * Wm1[(d+2)*HH + t];
    a3 += x[d+3] * Wm1[(d+3)*HH + t];
  }
  float v = a0 + a1 + a2 + a3 + bm1[t];
  tl[t] = v > 0.f ? v : 0.f;
  __syncthreads();
  if (t < 2){
    float s = bm2[t];
    for (int h = 0; h < HH; ++h) s += tl[h]*Wm2[h*2 + t];
    out[(long)DISROWS*30 + m*2 + t] = tanhf(s);
  }
}

// ---------------- launch ----------------
extern "C" void kernel_launch(void* const* d_in, const int* in_sizes, int n_in,
                              void* d_out, int out_size, void* d_ws, size_t ws_size,
                              hipStream_t stream){
  const float* lm   = (const float*)d_in[0];
  const float* nf   = (const float*)d_in[1];
  const float* ef   = (const float*)d_in[2];
  const int*   src  = (const int*)d_in[3];
  const int*   dst  = (const int*)d_in[4];
  const int*   midx = (const int*)d_in[5];
  const float* Wg0  = (const float*)d_in[6];
  const float* bg0  = (const float*)d_in[7];
  const float* Wg1  = (const float*)d_in[8];
  const float* bg1  = (const float*)d_in[9];
  const float* Wd1  = (const float*)d_in[10];
  const float* bd1  = (const float*)d_in[11];
  const float* Wd2  = (const float*)d_in[12];
  const float* bd2  = (const float*)d_in[13];
  const float* Wm1  = (const float*)d_in[14];
  const float* bm1  = (const float*)d_in[15];
  const float* Wm2  = (const float*)d_in[16];
  const float* bm2  = (const float*)d_in[17];
  float* dis = (float*)d_out;

  char* ws = (char*)d_ws;
  size_t off = 0;
  auto alloc = [&](size_t bytes)->void*{
    void* p = ws + off; off += (bytes + 255) & ~(size_t)255; return p;
  };
  float* x0   = (float*)alloc((size_t)NN*DD*4);
  float* yb   = (float*)alloc((size_t)NN*DD*4);
  float* hb   = (float*)alloc((size_t)NN*DD*4);
  float* ew   = (float*)alloc((size_t)EE*4);
  int*   offs = (int*)alloc((NN+1)*4);
  int*   sorted = (int*)alloc(EE*4);
  short* WtAh = (short*)alloc((size_t)DD*DD*2);
  short* WtAl = (short*)alloc((size_t)DD*DD*2);
  short* W1t  = (short*)alloc((size_t)HH*DD*2);
  short* W2t  = (short*)alloc((size_t)32*HH*2);
  float* P    = (float*)alloc((size_t)4*NN*DD*4);

  k_feat <<<dim3(384,5),256,0,stream>>>(lm, nf, x0);
  k_graph<<<1,1024,0,stream>>>(dst, ef, offs, sorted, ew);
  k_tsplit<<<dim3(2,20),256,0,stream>>>(Wd1, W1t, nullptr, DD, HH);
  k_wd2t<<<1,256,0,stream>>>(Wd2, W2t);

  k_tsplit<<<dim3(20,20),256,0,stream>>>(Wg0, WtAh, WtAl, DD, DD);
  k_agg<<<dim3(384,5),256,0,stream>>>(x0, ew, src, offs, sorted, yb);
  k_gin_gemm<<<dim3(3,10,4),256,0,stream>>>(yb, WtAh, WtAl, P);
  k_gin_reduce<<<480,256,0,stream>>>(P, bg0, nullptr, hb);

  k_tsplit<<<dim3(20,20),256,0,stream>>>(Wg1, WtAh, WtAl, DD, DD);
  k_agg<<<dim3(384,5),256,0,stream>>>(hb, ew, src, offs, sorted, yb);
  k_gin_gemm<<<dim3(3,10,4),256,0,stream>>>(yb, WtAh, WtAl, P);
  k_gin_reduce<<<480,256,0,stream>>>(P, bg1, x0, hb);

  k_dis<<<dim3(24,24),256,0,stream>>>(hb, W1t, bd1, W2t, bd2, dis);
  k_mask<<<64,128,0,stream>>>(hb, midx, Wm1, bm1, Wm2, bm2, dis);
}

// Round 3
// 214.138 us; speedup vs baseline: 1.9306x; 1.3532x over previous
//
#include <hip/hip_runtime.h>
#include <hip/hip_bf16.h>

#define NN 384
#define EE 12288
#define DD 1280
#define HH 128
#define DISROWS (NN*NN)

typedef short bf16x8 __attribute__((ext_vector_type(8)));
typedef float f32x4  __attribute__((ext_vector_type(4)));

__device__ __forceinline__ unsigned short f2bf(float x){
  unsigned u = __builtin_bit_cast(unsigned, x);
  u += 0x7fffu + ((u >> 16) & 1u);
  return (unsigned short)(u >> 16);
}
__device__ __forceinline__ float bf2f(unsigned short h){
  unsigned u = ((unsigned)h) << 16;
  return __builtin_bit_cast(float, u);
}
__device__ __forceinline__ short f2bf_fast(float x){
  return (short)__bfloat16_as_ushort(__float2bfloat16(x));
}

// ---------------- prep: feat concat (blocks 0..479) + graph CSR (block 480) ----------------
__global__ void k_prep(const float* __restrict__ lm, const float* __restrict__ nf,
                       float* __restrict__ x0,
                       const int* __restrict__ dst, const float* __restrict__ ef,
                       int* __restrict__ offs, int* __restrict__ sorted,
                       float* __restrict__ ew){
  __shared__ int cnt[512];
  __shared__ int base[NN];
  const int t = threadIdx.x;  // 1024
  if (blockIdx.x < 480){
    int i = blockIdx.x*1024 + t;
    int n = i / 1280;
    int d = i - n*1280;
    float v = (d < 1024) ? lm[(n+1)*1024 + d] : nf[n*256 + (d-1024)];
    x0[i] = v;
    return;
  }
  if (t < 512) cnt[t] = 0;
  __syncthreads();
  for (int e = t; e < EE; e += 1024){
    atomicAdd(&cnt[dst[e]], 1);
    float f = ef[e];
    ew[e] = 1.0f/(f*f + 1e-6f);
  }
  __syncthreads();
  for (int off = 1; off < 512; off <<= 1){
    int v = 0;
    if (t < 512 && t >= off) v = cnt[t - off];
    __syncthreads();
    if (t < 512) cnt[t] += v;
    __syncthreads();
  }
  if (t < NN){
    int excl = t ? cnt[t-1] : 0;
    offs[t] = excl;
    base[t] = excl;
  }
  if (t == 0) offs[NN] = EE;
  __syncthreads();
  for (int e = t; e < EE; e += 1024){
    int p = atomicAdd(&base[dst[e]], 1);
    sorted[p] = e;
  }
}

// y[v] = x[v] + sum_{e: dst==v} ew[e] * x[src[e]]
__global__ void k_agg(const float* __restrict__ X, const float* __restrict__ ew,
                      const int* __restrict__ src, const int* __restrict__ offs,
                      const int* __restrict__ sorted, float* __restrict__ Y){
  __shared__ int   s_off[160];
  __shared__ float s_w[160];
  const int v = blockIdx.x;
  const int d = blockIdx.y*256 + threadIdx.x;
  const int t = threadIdx.x;
  float acc = X[(long)v*DD + d];
  const int b = offs[v], e = offs[v+1];
  for (int c0 = b; c0 < e; c0 += 160){
    int n = e - c0; if (n > 160) n = 160;
    __syncthreads();
    if (t < n){
      int eid = sorted[c0 + t];
      s_off[t] = src[eid]*DD;
      s_w[t]   = ew[eid];
    }
    __syncthreads();
    int k = 0;
    for (; k + 4 <= n; k += 4){
      acc += s_w[k]  *X[s_off[k]   + d];
      acc += s_w[k+1]*X[s_off[k+1] + d];
      acc += s_w[k+2]*X[s_off[k+2] + d];
      acc += s_w[k+3]*X[s_off[k+3] + d];
    }
    for (; k < n; ++k) acc += s_w[k]*X[s_off[k] + d];
  }
  Y[(long)v*DD + d] = acc;
}

// transpose W[R][C] -> Thi/Tlo[C][R] as bf16 hi (+ optional lo residual)
__device__ __forceinline__ void tsplit_body(const float* __restrict__ W,
                                            short* __restrict__ Thi, short* __restrict__ Tlo,
                                            int R, int C, int bx, int by, int t){
  __shared__ float tile[64][65];
  int rb = by*64, cb = bx*64;
  int r  = t >> 2;
  int cs = (t & 3) * 16;
  const float* sp = W + (long)(rb + r)*C + cb + cs;
  #pragma unroll
  for (int i = 0; i < 16; i += 4){
    f32x4 v = *(const f32x4*)(sp + i);
    tile[r][cs+i+0] = v[0]; tile[r][cs+i+1] = v[1];
    tile[r][cs+i+2] = v[2]; tile[r][cs+i+3] = v[3];
  }
  __syncthreads();
  int cp = t >> 2;
  int rs = (t & 3) * 16;
  bf16x8 vh0, vh1, vl0, vl1;
  #pragma unroll
  for (int i = 0; i < 8; ++i){
    float f = tile[rs+i][cp];
    unsigned short h = f2bf(f);
    vh0[i] = (short)h; vl0[i] = (short)f2bf(f - bf2f(h));
  }
  #pragma unroll
  for (int i = 0; i < 8; ++i){
    float f = tile[rs+8+i][cp];
    unsigned short h = f2bf(f);
    vh1[i] = (short)h; vl1[i] = (short)f2bf(f - bf2f(h));
  }
  long ob = (long)(cb + cp)*R + rb + rs;
  *(bf16x8*)&Thi[ob]   = vh0;
  *(bf16x8*)&Thi[ob+8] = vh1;
  if (Tlo){
    *(bf16x8*)&Tlo[ob]   = vl0;
    *(bf16x8*)&Tlo[ob+8] = vl1;
  }
}

__global__ void k_tsplit(const float* __restrict__ W, short* __restrict__ Thi,
                         short* __restrict__ Tlo, int R, int C){
  tsplit_body(W, Thi, Tlo, R, C, blockIdx.x, blockIdx.y, threadIdx.x);
}

// blocks 0..39: Wd1 transpose (bx=b%2, by=b/2); block 40: Wd2 pack
__global__ void k_dw(const float* __restrict__ Wd1, short* __restrict__ W1t,
                     const float* __restrict__ Wd2, short* __restrict__ W2t){
  int b = blockIdx.x, t = threadIdx.x;
  if (b < 40){
    tsplit_body(Wd1, W1t, nullptr, DD, HH, b & 1, b >> 1, t);
    return;
  }
  for (int i = t; i < 32*HH; i += 256){
    int c = i >> 7, h = i & 127;
    float v = (c < 30) ? Wd2[h*30 + c] : 0.f;
    W2t[i] = (short)f2bf(v);
  }
}

// ---------------- GIN GEMM, split-K=4 ----------------
__launch_bounds__(256, 2)
__global__ void k_gin_gemm(const float* __restrict__ Y, const short* __restrict__ Whi,
                           const short* __restrict__ Wlo, float* __restrict__ P){
  __shared__ __align__(16) short Ahi[128*40], Alo[128*40], Bhi[128*40], Blo[128*40];
  const int m0 = blockIdx.x*128;
  const int n0 = blockIdx.y*128;
  const int kbase = blockIdx.z*320;
  const int t = threadIdx.x, w = t >> 6, lane = t & 63;
  const int l15 = lane & 15, l4 = lane >> 4;
  f32x4 acc[2][8];
  #pragma unroll
  for (int m = 0; m < 2; ++m)
    #pragma unroll
    for (int n = 0; n < 8; ++n) acc[m][n] = (f32x4){0.f,0.f,0.f,0.f};

  const int row = t >> 1, half = t & 1;
  const float* ap  = Y   + (long)(m0+row)*DD + half*16;
  const short* bph = Whi + (long)(n0+row)*DD + half*16;
  const short* bpl = Wlo + (long)(n0+row)*DD + half*16;

  for (int kk = 0; kk < 10; ++kk){
    int d0 = kbase + kk*32;
    __syncthreads();
    #pragma unroll
    for (int g = 0; g < 2; ++g){
      f32x4 v0 = *(const f32x4*)(ap + d0 + g*8);
      f32x4 v1 = *(const f32x4*)(ap + d0 + g*8 + 4);
      bf16x8 vh, vl;
      #pragma unroll
      for (int q = 0; q < 4; ++q){
        unsigned short h0 = f2bf(v0[q]);
        vh[q]   = (short)h0; vl[q]   = (short)f2bf(v0[q] - bf2f(h0));
        unsigned short h1 = f2bf(v1[q]);
        vh[4+q] = (short)h1; vl[4+q] = (short)f2bf(v1[q] - bf2f(h1));
      }
      *(bf16x8*)&Ahi[row*40 + half*16 + g*8] = vh;
      *(bf16x8*)&Alo[row*40 + half*16 + g*8] = vl;
    }
    *(bf16x8*)&Bhi[row*40 + half*16]     = *(const bf16x8*)(bph + d0);
    *(bf16x8*)&Bhi[row*40 + half*16 + 8] = *(const bf16x8*)(bph + d0 + 8);
    *(bf16x8*)&Blo[row*40 + half*16]     = *(const bf16x8*)(bpl + d0);
    *(bf16x8*)&Blo[row*40 + half*16 + 8] = *(const bf16x8*)(bpl + d0 + 8);
    __syncthreads();

    bf16x8 ah[2], al[2];
    #pragma unroll
    for (int m = 0; m < 2; ++m){
      int rr = w*32 + m*16 + l15;
      ah[m] = *(const bf16x8*)&Ahi[rr*40 + l4*8];
      al[m] = *(const bf16x8*)&Alo[rr*40 + l4*8];
    }
    #pragma unroll
    for (int n = 0; n < 8; ++n){
      int rr = n*16 + l15;
      bf16x8 bh = *(const bf16x8*)&Bhi[rr*40 + l4*8];
      bf16x8 bl = *(const bf16x8*)&Blo[rr*40 + l4*8];
      #pragma unroll
      for (int m = 0; m < 2; ++m){
        acc[m][n] = __builtin_amdgcn_mfma_f32_16x16x32_bf16(ah[m], bh, acc[m][n], 0,0,0);
        acc[m][n] = __builtin_amdgcn_mfma_f32_16x16x32_bf16(ah[m], bl, acc[m][n], 0,0,0);
        acc[m][n] = __builtin_amdgcn_mfma_f32_16x16x32_bf16(al[m], bh, acc[m][n], 0,0,0);
      }
    }
  }
  float* Pz = P + (long)blockIdx.z*NN*DD;
  #pragma unroll
  for (int m = 0; m < 2; ++m){
    #pragma unroll
    for (int n = 0; n < 8; ++n){
      int gr0 = m0 + w*32 + m*16 + l4*4;
      int gc  = n0 + n*16 + l15;
      #pragma unroll
      for (int r = 0; r < 4; ++r)
        Pz[(long)(gr0+r)*DD + gc] = acc[m][n][r];
    }
  }
}

__global__ void k_gin_reduce(const float* __restrict__ P, const float* __restrict__ bias,
                             const float* __restrict__ resid, float* __restrict__ Out){
  const int i = blockIdx.x*256 + threadIdx.x;
  const int col = (i*4) % DD;
  const f32x4* P4 = (const f32x4*)P;
  f32x4 s = P4[i];
  s += P4[i + 122880];
  s += P4[i + 2*122880];
  s += P4[i + 3*122880];
  s += *(const f32x4*)(bias + col);
  if (resid) s += ((const f32x4*)resid)[i];
  ((f32x4*)Out)[i] = s;
}

// ---------------- fused dis MLP v3 ----------------
// 512 thr / 8 waves; tile 16i x 16j; wave w owns i_local {2w, 2w+1}.
// LDS: W dbuf [2][128][40]s + XI dbuf [2][16][36]f + XJ dbuf [2][16][36]f (29696B),
// layer-2 t-buffer aliases all of it (34816B).
__launch_bounds__(512, 4)
__global__ void k_dis(const float* __restrict__ X, const short* __restrict__ W1t,
                      const float* __restrict__ bd1, const short* __restrict__ W2t,
                      const float* __restrict__ bd2, float* __restrict__ out){
  __shared__ __align__(16) short smem[17408];   // 34816 B
  short* WT  = smem;                            // [2][5120] shorts
  float* XIf = (float*)(smem + 10240);          // [2][576] floats
  float* XJf = (float*)(smem + 12544);          // [2][576] floats
  short* TL  = smem;                            // layer-2 alias [128][136]

  const int t = threadIdx.x, w = t >> 6, lane = t & 63;
  const int l15 = lane & 15, l4 = lane >> 4;
  const int i0 = blockIdx.y*16, j0 = blockIdx.x*16;

  f32x4 acc[2][8];
  #pragma unroll
  for (int m = 0; m < 2; ++m)
    #pragma unroll
    for (int n = 0; n < 8; ++n) acc[m][n] = (f32x4){0.f,0.f,0.f,0.f};

  // staging assignments
  const int swr = t >> 2, swq = t & 3;                 // W: 128 rows x 4 chunks of 8 shorts
  const short* wsrc = W1t + (long)swr*DD + swq*8;
  const int sxr = t >> 5, sxc = t & 31;                // X: 16 rows x 32 cols
  const float* xisrc = X + (long)(i0+sxr)*DD + sxc;
  const float* xjsrc = X + (long)(j0+sxr)*DD + sxc;

  // prologue: stage k-step 0 into buffer 0
  *(bf16x8*)&WT[swr*40 + swq*8] = *(const bf16x8*)wsrc;
  XIf[sxr*36 + sxc] = xisrc[0];
  XJf[sxr*36 + sxc] = xjsrc[0];
  __syncthreads();

  for (int kk = 0; kk < 40; ++kk){
    const int cur = kk & 1, nxt = cur ^ 1;
    bf16x8 wv; float xiv, xjv;
    if (kk < 39){
      const int d1 = (kk+1)*32;
      wv  = *(const bf16x8*)(wsrc + d1);
      xiv = xisrc[d1];
      xjv = xjsrc[d1];
    }
    // A fragments from LDS
    f32x4 xj0 = *(const f32x4*)&XJf[cur*576 + l15*36 + l4*8];
    f32x4 xj1 = *(const f32x4*)&XJf[cur*576 + l15*36 + l4*8 + 4];
    bf16x8 a[2];
    #pragma unroll
    for (int m = 0; m < 2; ++m){
      const int im = w*2 + m;
      f32x4 xi0 = *(const f32x4*)&XIf[cur*576 + im*36 + l4*8];
      f32x4 xi1 = *(const f32x4*)&XIf[cur*576 + im*36 + l4*8 + 4];
      bf16x8 av;
      #pragma unroll
      for (int q = 0; q < 4; ++q){ float dl = xj0[q]-xi0[q]; av[q]   = f2bf_fast(dl*dl); }
      #pragma unroll
      for (int q = 0; q < 4; ++q){ float dl = xj1[q]-xi1[q]; av[4+q] = f2bf_fast(dl*dl); }
      a[m] = av;
    }
    #pragma unroll
    for (int n = 0; n < 8; ++n){
      bf16x8 b = *(const bf16x8*)&WT[cur*5120 + (n*16 + l15)*40 + l4*8];
      acc[0][n] = __builtin_amdgcn_mfma_f32_16x16x32_bf16(a[0], b, acc[0][n], 0,0,0);
      acc[1][n] = __builtin_amdgcn_mfma_f32_16x16x32_bf16(a[1], b, acc[1][n], 0,0,0);
    }
    if (kk < 39){
      *(bf16x8*)&WT[nxt*5120 + swr*40 + swq*8] = wv;
      XIf[nxt*576 + sxr*36 + sxc] = xiv;
      XJf[nxt*576 + sxr*36 + sxc] = xjv;
    }
    __syncthreads();
  }

  // layer 2 in two chunks of 128 pairs; wave w owns pairs [w*32, w*32+32)
  float b1v[8];
  #pragma unroll
  for (int n = 0; n < 8; ++n) b1v[n] = bd1[n*16 + l15];

  #pragma unroll
  for (int c = 0; c < 2; ++c){
    if ((w >> 2) == c){
      #pragma unroll
      for (int m = 0; m < 2; ++m){
        int lp0 = ((w & 3)*2 + m)*16 + l4*4;
        #pragma unroll
        for (int n = 0; n < 8; ++n){
          int h = n*16 + l15;
          #pragma unroll
          for (int r = 0; r < 4; ++r){
            float v = acc[m][n][r] + b1v[n];
            v = v > 0.f ? v : 0.f;
            TL[(lp0 + r)*136 + h] = f2bf_fast(v);
          }
        }
      }
    }
    __syncthreads();

    f32x4 acc2[2];
    acc2[0] = (f32x4){0.f,0.f,0.f,0.f};
    acc2[1] = (f32x4){0.f,0.f,0.f,0.f};
    #pragma unroll
    for (int hs = 0; hs < 4; ++hs){
      bf16x8 a2 = *(const bf16x8*)&TL[(w*16 + l15)*136 + hs*32 + l4*8];
      #pragma unroll
      for (int nn = 0; nn < 2; ++nn){
        bf16x8 b2 = *(const bf16x8*)&W2t[(nn*16 + l15)*HH + hs*32 + l4*8];
        acc2[nn] = __builtin_amdgcn_mfma_f32_16x16x32_bf16(a2, b2, acc2[nn], 0,0,0);
      }
    }
    #pragma unroll
    for (int nn = 0; nn < 2; ++nn){
      int cc = nn*16 + l15;
      if (cc < 30){
        float b2v = bd2[cc];
        #pragma unroll
        for (int r = 0; r < 4; ++r){
          int gp = c*128 + w*16 + l4*4 + r;
          int gi = i0 + (gp >> 4), gj = j0 + (gp & 15);
          out[((long)gi*NN + gj)*30 + cc] = acc2[nn][r] + b2v;
        }
      }
    }
    if (c == 0) __syncthreads();
  }
}

// ---------------- mask head ----------------
__global__ void k_mask(const float* __restrict__ X, const int* __restrict__ midx,
                       const float* __restrict__ Wm1, const float* __restrict__ bm1,
                       const float* __restrict__ Wm2, const float* __restrict__ bm2,
                       float* __restrict__ out){
  __shared__ float tl[HH];
  int m = blockIdx.x, t = threadIdx.x;   // 128 threads
  const float* x = X + (long)midx[m]*DD;
  float a0 = 0.f, a1 = 0.f, a2 = 0.f, a3 = 0.f;
  for (int d = 0; d < DD; d += 4){
    a0 += x[d]   * Wm1[(d)*HH + t];
    a1 += x[d+1] * Wm1[(d+1)*HH + t];
    a2 += x[d+2] * Wm1[(d+2)*HH + t];
    a3 += x[d+3] * Wm1[(d+3)*HH + t];
  }
  float v = a0 + a1 + a2 + a3 + bm1[t];
  tl[t] = v > 0.f ? v : 0.f;
  __syncthreads();
  if (t < 2){
    float s = bm2[t];
    for (int h = 0; h < HH; ++h) s += tl[h]*Wm2[h*2 + t];
    out[(long)DISROWS*30 + m*2 + t] = tanhf(s);
  }
}

// ---------------- launch ----------------
extern "C" void kernel_launch(void* const* d_in, const int* in_sizes, int n_in,
                              void* d_out, int out_size, void* d_ws, size_t ws_size,
                              hipStream_t stream){
  const float* lm   = (const float*)d_in[0];
  const float* nf   = (const float*)d_in[1];
  const float* ef   = (const float*)d_in[2];
  const int*   src  = (const int*)d_in[3];
  const int*   dst  = (const int*)d_in[4];
  const int*   midx = (const int*)d_in[5];
  const float* Wg0  = (const float*)d_in[6];
  const float* bg0  = (const float*)d_in[7];
  const float* Wg1  = (const float*)d_in[8];
  const float* bg1  = (const float*)d_in[9];
  const float* Wd1  = (const float*)d_in[10];
  const float* bd1  = (const float*)d_in[11];
  const float* Wd2  = (const float*)d_in[12];
  const float* bd2  = (const float*)d_in[13];
  const float* Wm1  = (const float*)d_in[14];
  const float* bm1  = (const float*)d_in[15];
  const float* Wm2  = (const float*)d_in[16];
  const float* bm2  = (const float*)d_in[17];
  float* dis = (float*)d_out;

  char* ws = (char*)d_ws;
  size_t off = 0;
  auto alloc = [&](size_t bytes)->void*{
    void* p = ws + off; off += (bytes + 255) & ~(size_t)255; return p;
  };
  float* x0   = (float*)alloc((size_t)NN*DD*4);
  float* yb   = (float*)alloc((size_t)NN*DD*4);
  float* hb   = (float*)alloc((size_t)NN*DD*4);
  float* ew   = (float*)alloc((size_t)EE*4);
  int*   offs = (int*)alloc((NN+1)*4);
  int*   sorted = (int*)alloc(EE*4);
  short* WtAh = (short*)alloc((size_t)DD*DD*2);
  short* WtAl = (short*)alloc((size_t)DD*DD*2);
  short* W1t  = (short*)alloc((size_t)HH*DD*2);
  short* W2t  = (short*)alloc((size_t)32*HH*2);
  float* P    = (float*)alloc((size_t)4*NN*DD*4);

  k_prep<<<481,1024,0,stream>>>(lm, nf, x0, dst, ef, offs, sorted, ew);
  k_dw  <<<41,256,0,stream>>>(Wd1, W1t, Wd2, W2t);

  k_tsplit<<<dim3(20,20),256,0,stream>>>(Wg0, WtAh, WtAl, DD, DD);
  k_agg<<<dim3(384,5),256,0,stream>>>(x0, ew, src, offs, sorted, yb);
  k_gin_gemm<<<dim3(3,10,4),256,0,stream>>>(yb, WtAh, WtAl, P);
  k_gin_reduce<<<480,256,0,stream>>>(P, bg0, nullptr, hb);

  k_tsplit<<<dim3(20,20),256,0,stream>>>(Wg1, WtAh, WtAl, DD, DD);
  k_agg<<<dim3(384,5),256,0,stream>>>(hb, ew, src, offs, sorted, yb);
  k_gin_gemm<<<dim3(3,10,4),256,0,stream>>>(yb, WtAh, WtAl, P);
  k_gin_reduce<<<480,256,0,stream>>>(P, bg1, x0, hb);

  k_dis<<<dim3(24,24),512,0,stream>>>(hb, W1t, bd1, W2t, bd2, dis);
  k_mask<<<64,128,0,stream>>>(hb, midx, Wm1, bm1, Wm2, bm2, dis);
}

// Round 4
// 205.459 us; speedup vs baseline: 2.0122x; 1.0422x over previous
//
#include <hip/hip_runtime.h>
#include <hip/hip_bf16.h>

#define NN 384
#define EE 12288
#define DD 1280
#define HH 128
#define DISROWS (NN*NN)

typedef short bf16x8 __attribute__((ext_vector_type(8)));
typedef float f32x4  __attribute__((ext_vector_type(4)));

__device__ __forceinline__ unsigned short f2bf(float x){
  unsigned u = __builtin_bit_cast(unsigned, x);
  u += 0x7fffu + ((u >> 16) & 1u);
  return (unsigned short)(u >> 16);
}
__device__ __forceinline__ float bf2f(unsigned short h){
  unsigned u = ((unsigned)h) << 16;
  return __builtin_bit_cast(float, u);
}
__device__ __forceinline__ short f2bf_fast(float x){
  return (short)__bfloat16_as_ushort(__float2bfloat16(x));
}

// transpose W[R][C] -> Thi/Tlo[C][R] as bf16 hi (+ optional lo residual). 256 threads.
__device__ __forceinline__ void tsplit_body(const float* __restrict__ W,
                                            short* __restrict__ Thi, short* __restrict__ Tlo,
                                            int R, int C, int bx, int by, int t,
                                            float* tile /* [64][65] shared */){
  int rb = by*64, cb = bx*64;
  int r  = t >> 2;
  int cs = (t & 3) * 16;
  const float* sp = W + (long)(rb + r)*C + cb + cs;
  #pragma unroll
  for (int i = 0; i < 16; i += 4){
    f32x4 v = *(const f32x4*)(sp + i);
    tile[r*65 + cs+i+0] = v[0]; tile[r*65 + cs+i+1] = v[1];
    tile[r*65 + cs+i+2] = v[2]; tile[r*65 + cs+i+3] = v[3];
  }
  __syncthreads();
  int cp = t >> 2;
  int rs = (t & 3) * 16;
  bf16x8 vh0, vh1, vl0, vl1;
  #pragma unroll
  for (int i = 0; i < 8; ++i){
    float f = tile[(rs+i)*65 + cp];
    unsigned short h = f2bf(f);
    vh0[i] = (short)h; vl0[i] = (short)f2bf(f - bf2f(h));
  }
  #pragma unroll
  for (int i = 0; i < 8; ++i){
    float f = tile[(rs+8+i)*65 + cp];
    unsigned short h = f2bf(f);
    vh1[i] = (short)h; vl1[i] = (short)f2bf(f - bf2f(h));
  }
  long ob = (long)(cb + cp)*R + rb + rs;
  *(bf16x8*)&Thi[ob]   = vh0;
  *(bf16x8*)&Thi[ob+8] = vh1;
  if (Tlo){
    *(bf16x8*)&Tlo[ob]   = vl0;
    *(bf16x8*)&Tlo[ob+8] = vl1;
  }
}

// ---------------- mega-prep (512 thr): feat | graph CSR | Wd prep | tsplit(Wg0) ----------------
// blocks: [0,960) feat; [960] graph; [961,1002) dw; [1002,1402) tsplit Wg0
__global__ void k_prep(const float* __restrict__ lm, const float* __restrict__ nf,
                       float* __restrict__ x0,
                       const int* __restrict__ dst, const float* __restrict__ ef,
                       int* __restrict__ offs, int* __restrict__ sorted,
                       float* __restrict__ ew,
                       const float* __restrict__ Wd1, short* __restrict__ W1t,
                       const float* __restrict__ Wd2, short* __restrict__ W2t,
                       const float* __restrict__ Wg0, short* __restrict__ WtAh,
                       short* __restrict__ WtAl){
  __shared__ __align__(16) float sh[64*65];   // tsplit tile; graph aliases as int
  const int b = blockIdx.x;
  const int t = threadIdx.x;  // 512
  if (b < 960){
    int i = b*512 + t;
    int n = i / 1280;
    int d = i - n*1280;
    x0[i] = (d < 1024) ? lm[(n+1)*1024 + d] : nf[n*256 + (d-1024)];
    return;
  }
  if (b == 960){
    int* cnt = (int*)sh;
    int* base = cnt + 512;
    if (t < 512) cnt[t] = 0;
    __syncthreads();
    for (int e = t; e < EE; e += 512){
      atomicAdd(&cnt[dst[e]], 1);
      float f = ef[e];
      ew[e] = 1.0f/(f*f + 1e-6f);
    }
    __syncthreads();
    for (int off = 1; off < 512; off <<= 1){
      int v = (t >= off) ? cnt[t - off] : 0;
      __syncthreads();
      cnt[t] += v;
      __syncthreads();
    }
    if (t < NN){
      int excl = t ? cnt[t-1] : 0;
      offs[t] = excl;
      base[t] = excl;
    }
    if (t == 0) offs[NN] = EE;
    __syncthreads();
    for (int e = t; e < EE; e += 512){
      int p = atomicAdd(&base[dst[e]], 1);
      sorted[p] = e;
    }
    return;
  }
  if (b < 1002){
    int g = b - 961;
    if (g < 40){
      if (t < 256) tsplit_body(Wd1, W1t, nullptr, DD, HH, g & 1, g >> 1, t, sh);
      else { __syncthreads(); }  // match tsplit_body's barrier
      return;
    }
    // g == 40: Wd2 pack
    for (int i = t; i < 32*HH; i += 512){
      int c = i >> 7, h = i & 127;
      float v = (c < 30) ? Wd2[h*30 + c] : 0.f;
      W2t[i] = (short)f2bf(v);
    }
    return;
  }
  {
    int g = b - 1002;
    if (t < 256) tsplit_body(Wg0, WtAh, WtAl, DD, DD, g % 20, g / 20, t, sh);
    else { __syncthreads(); }
  }
}

// ---------------- edge aggregation ----------------
__global__ void k_agg(const float* __restrict__ X, const float* __restrict__ ew,
                      const int* __restrict__ src, const int* __restrict__ offs,
                      const int* __restrict__ sorted, float* __restrict__ Y){
  __shared__ int   s_off[160];
  __shared__ float s_w[160];
  const int v = blockIdx.x;
  const int d = blockIdx.y*256 + threadIdx.x;
  const int t = threadIdx.x;
  float acc = X[(long)v*DD + d];
  const int b = offs[v], e = offs[v+1];
  for (int c0 = b; c0 < e; c0 += 160){
    int n = e - c0; if (n > 160) n = 160;
    __syncthreads();
    if (t < n){
      int eid = sorted[c0 + t];
      s_off[t] = src[eid]*DD;
      s_w[t]   = ew[eid];
    }
    __syncthreads();
    int k = 0;
    for (; k + 4 <= n; k += 4){
      acc += s_w[k]  *X[s_off[k]   + d];
      acc += s_w[k+1]*X[s_off[k+1] + d];
      acc += s_w[k+2]*X[s_off[k+2] + d];
      acc += s_w[k+3]*X[s_off[k+3] + d];
    }
    for (; k < n; ++k) acc += s_w[k]*X[s_off[k] + d];
  }
  Y[(long)v*DD + d] = acc;
}

// ---------------- GIN GEMM, split-K=4 ----------------
__launch_bounds__(256, 2)
__global__ void k_gin_gemm(const float* __restrict__ Y, const short* __restrict__ Whi,
                           const short* __restrict__ Wlo, float* __restrict__ P){
  __shared__ __align__(16) short Ahi[128*40], Alo[128*40], Bhi[128*40], Blo[128*40];
  const int m0 = blockIdx.x*128;
  const int n0 = blockIdx.y*128;
  const int kbase = blockIdx.z*320;
  const int t = threadIdx.x, w = t >> 6, lane = t & 63;
  const int l15 = lane & 15, l4 = lane >> 4;
  f32x4 acc[2][8];
  #pragma unroll
  for (int m = 0; m < 2; ++m)
    #pragma unroll
    for (int n = 0; n < 8; ++n) acc[m][n] = (f32x4){0.f,0.f,0.f,0.f};

  const int row = t >> 1, half = t & 1;
  const float* ap  = Y   + (long)(m0+row)*DD + half*16;
  const short* bph = Whi + (long)(n0+row)*DD + half*16;
  const short* bpl = Wlo + (long)(n0+row)*DD + half*16;

  for (int kk = 0; kk < 10; ++kk){
    int d0 = kbase + kk*32;
    __syncthreads();
    #pragma unroll
    for (int g = 0; g < 2; ++g){
      f32x4 v0 = *(const f32x4*)(ap + d0 + g*8);
      f32x4 v1 = *(const f32x4*)(ap + d0 + g*8 + 4);
      bf16x8 vh, vl;
      #pragma unroll
      for (int q = 0; q < 4; ++q){
        unsigned short h0 = f2bf(v0[q]);
        vh[q]   = (short)h0; vl[q]   = (short)f2bf(v0[q] - bf2f(h0));
        unsigned short h1 = f2bf(v1[q]);
        vh[4+q] = (short)h1; vl[4+q] = (short)f2bf(v1[q] - bf2f(h1));
      }
      *(bf16x8*)&Ahi[row*40 + half*16 + g*8] = vh;
      *(bf16x8*)&Alo[row*40 + half*16 + g*8] = vl;
    }
    *(bf16x8*)&Bhi[row*40 + half*16]     = *(const bf16x8*)(bph + d0);
    *(bf16x8*)&Bhi[row*40 + half*16 + 8] = *(const bf16x8*)(bph + d0 + 8);
    *(bf16x8*)&Blo[row*40 + half*16]     = *(const bf16x8*)(bpl + d0);
    *(bf16x8*)&Blo[row*40 + half*16 + 8] = *(const bf16x8*)(bpl + d0 + 8);
    __syncthreads();

    bf16x8 ah[2], al[2];
    #pragma unroll
    for (int m = 0; m < 2; ++m){
      int rr = w*32 + m*16 + l15;
      ah[m] = *(const bf16x8*)&Ahi[rr*40 + l4*8];
      al[m] = *(const bf16x8*)&Alo[rr*40 + l4*8];
    }
    #pragma unroll
    for (int n = 0; n < 8; ++n){
      int rr = n*16 + l15;
      bf16x8 bh = *(const bf16x8*)&Bhi[rr*40 + l4*8];
      bf16x8 bl = *(const bf16x8*)&Blo[rr*40 + l4*8];
      #pragma unroll
      for (int m = 0; m < 2; ++m){
        acc[m][n] = __builtin_amdgcn_mfma_f32_16x16x32_bf16(ah[m], bh, acc[m][n], 0,0,0);
        acc[m][n] = __builtin_amdgcn_mfma_f32_16x16x32_bf16(ah[m], bl, acc[m][n], 0,0,0);
        acc[m][n] = __builtin_amdgcn_mfma_f32_16x16x32_bf16(al[m], bh, acc[m][n], 0,0,0);
      }
    }
  }
  float* Pz = P + (long)blockIdx.z*NN*DD;
  #pragma unroll
  for (int m = 0; m < 2; ++m){
    #pragma unroll
    for (int n = 0; n < 8; ++n){
      int gr0 = m0 + w*32 + m*16 + l4*4;
      int gc  = n0 + n*16 + l15;
      #pragma unroll
      for (int r = 0; r < 4; ++r)
        Pz[(long)(gr0+r)*DD + gc] = acc[m][n][r];
    }
  }
}

// red: blocks [0,480) sum P + bias (+resid) -> Out; blocks [480,880): tsplit(Wg1) -> WtA
__global__ void k_red_t(const float* __restrict__ P, const float* __restrict__ bias,
                        const float* __restrict__ resid, float* __restrict__ Out,
                        const float* __restrict__ Wg1, short* __restrict__ WtAh,
                        short* __restrict__ WtAl){
  __shared__ __align__(16) float sh[64*65];
  const int b = blockIdx.x;
  if (b >= 480){
    if (Wg1){
      int g = b - 480;
      tsplit_body(Wg1, WtAh, WtAl, DD, DD, g % 20, g / 20, threadIdx.x, sh);
    }
    return;
  }
  const int i = b*256 + threadIdx.x;
  const int col = (i*4) % DD;
  const f32x4* P4 = (const f32x4*)P;
  f32x4 s = P4[i];
  s += P4[i + 122880];
  s += P4[i + 2*122880];
  s += P4[i + 3*122880];
  s += *(const f32x4*)(bias + col);
  if (resid) s += ((const f32x4*)resid)[i];
  ((f32x4*)Out)[i] = s;
}

// ---------------- fused dis MLP v4 + mask head ----------------
// dis blocks [0,1152): 256 thr / 4 waves; tile 8i x 16j; wave w owns i {2w, 2w+1}.
// X read direct from global (L2-hot) with 1-iter register prefetch.
// LDS: W dbuf [2][128][40]s = 20480B; layer-2 TL alias [128][136]s = 34816B total.
// mask blocks [1152,1216): node = b-1152, threads t<128 active.
__launch_bounds__(256, 4)
__global__ void k_dis(const float* __restrict__ X, const short* __restrict__ W1t,
                      const float* __restrict__ bd1, const short* __restrict__ W2t,
                      const float* __restrict__ bd2, float* __restrict__ out,
                      const int* __restrict__ midx,
                      const float* __restrict__ Wm1, const float* __restrict__ bm1,
                      const float* __restrict__ Wm2, const float* __restrict__ bm2){
  __shared__ __align__(16) short smem[17408];   // 34816 B
  const int b = blockIdx.x;
  const int t = threadIdx.x;

  if (b >= 1152){
    // ---- mask head ----
    float* tl = (float*)smem;
    int m = b - 1152;
    if (t < HH){
      const float* x = X + (long)midx[m]*DD;
      float a0 = 0.f, a1 = 0.f, a2 = 0.f, a3 = 0.f;
      for (int d = 0; d < DD; d += 4){
        a0 += x[d]   * Wm1[(d)*HH + t];
        a1 += x[d+1] * Wm1[(d+1)*HH + t];
        a2 += x[d+2] * Wm1[(d+2)*HH + t];
        a3 += x[d+3] * Wm1[(d+3)*HH + t];
      }
      float v = a0 + a1 + a2 + a3 + bm1[t];
      tl[t] = v > 0.f ? v : 0.f;
    }
    __syncthreads();
    if (t < 2){
      float s = bm2[t];
      for (int h = 0; h < HH; ++h) s += tl[h]*Wm2[h*2 + t];
      out[(long)DISROWS*30 + m*2 + t] = tanhf(s);
    }
    return;
  }

  const int w = t >> 6, lane = t & 63;
  const int l15 = lane & 15, l4 = lane >> 4;
  const int jb = b % 24, ib = b / 24;
  const int i0 = ib*8, j0 = jb*16;

  f32x4 acc[2][8];
  #pragma unroll
  for (int m = 0; m < 2; ++m)
    #pragma unroll
    for (int n = 0; n < 8; ++n) acc[m][n] = (f32x4){0.f,0.f,0.f,0.f};

  // W staging: thread t handles row t>>1, half t&1 (32 shorts per K-step among 256 thr)
  const int woff = (t>>1)*40 + (t&1)*16;
  const short* wsrc = W1t + (long)(t>>1)*DD + (t&1)*16;
  // X pointers
  const float* xj_p  = X + (long)(j0 + l15)*DD + l4*8;
  const float* xi_p0 = X + (long)(i0 + 2*w)*DD + l4*8;
  const float* xi_p1 = xi_p0 + DD;

  // prologue: W k=0 -> LDS buf0; W k=1 -> regs; X k=0 -> regs
  bf16x8 wr0 = *(const bf16x8*)(wsrc);
  bf16x8 wr1 = *(const bf16x8*)(wsrc + 8);
  *(bf16x8*)&smem[woff]     = wr0;
  *(bf16x8*)&smem[woff + 8] = wr1;
  wr0 = *(const bf16x8*)(wsrc + 32);
  wr1 = *(const bf16x8*)(wsrc + 40);
  f32x4 xj0 = *(const f32x4*)(xj_p);
  f32x4 xj1 = *(const f32x4*)(xj_p + 4);
  f32x4 xA0 = *(const f32x4*)(xi_p0);
  f32x4 xA1 = *(const f32x4*)(xi_p0 + 4);
  f32x4 xB0 = *(const f32x4*)(xi_p1);
  f32x4 xB1 = *(const f32x4*)(xi_p1 + 4);
  __syncthreads();

  for (int kk = 0; kk < 40; ++kk){
    const int cur = (kk & 1) ? 5120 : 0;
    const int nxt = 5120 - cur;
    // construct A fragments from current X regs
    bf16x8 a0, a1;
    #pragma unroll
    for (int q = 0; q < 4; ++q){
      float d0 = xj0[q]-xA0[q]; a0[q]   = f2bf_fast(d0*d0);
      float d1 = xj1[q]-xA1[q]; a0[4+q] = f2bf_fast(d1*d1);
      float d2 = xj0[q]-xB0[q]; a1[q]   = f2bf_fast(d2*d2);
      float d3 = xj1[q]-xB1[q]; a1[4+q] = f2bf_fast(d3*d3);
    }
    // prefetch X for kk+1
    if (kk < 39){
      const int d1 = (kk+1)*32;
      xj0 = *(const f32x4*)(xj_p + d1);
      xj1 = *(const f32x4*)(xj_p + d1 + 4);
      xA0 = *(const f32x4*)(xi_p0 + d1);
      xA1 = *(const f32x4*)(xi_p0 + d1 + 4);
      xB0 = *(const f32x4*)(xi_p1 + d1);
      xB1 = *(const f32x4*)(xi_p1 + d1 + 4);
      // write W for kk+1 (loaded 1 iter ago) into the free buffer
      *(bf16x8*)&smem[nxt + woff]     = wr0;
      *(bf16x8*)&smem[nxt + woff + 8] = wr1;
    }
    // global W load for kk+2
    if (kk < 38){
      wr0 = *(const bf16x8*)(wsrc + (kk+2)*32);
      wr1 = *(const bf16x8*)(wsrc + (kk+2)*32 + 8);
    }
    #pragma unroll
    for (int n = 0; n < 8; ++n){
      bf16x8 bfr = *(const bf16x8*)&smem[cur + (n*16 + l15)*40 + l4*8];
      acc[0][n] = __builtin_amdgcn_mfma_f32_16x16x32_bf16(a0, bfr, acc[0][n], 0,0,0);
      acc[1][n] = __builtin_amdgcn_mfma_f32_16x16x32_bf16(a1, bfr, acc[1][n], 0,0,0);
    }
    __syncthreads();
  }

  // ---- layer 2 (fused): TL[128 pairs][136] aliases smem ----
  float b1v[8];
  #pragma unroll
  for (int n = 0; n < 8; ++n) b1v[n] = bd1[n*16 + l15];
  #pragma unroll
  for (int m = 0; m < 2; ++m){
    int p0 = (2*w + m)*16 + l4*4;
    #pragma unroll
    for (int n = 0; n < 8; ++n){
      int h = n*16 + l15;
      #pragma unroll
      for (int r = 0; r < 4; ++r){
        float v = acc[m][n][r] + b1v[n];
        v = v > 0.f ? v : 0.f;
        smem[(p0 + r)*136 + h] = f2bf_fast(v);
      }
    }
  }
  __syncthreads();

  f32x4 acc2[2][2];
  #pragma unroll
  for (int m2 = 0; m2 < 2; ++m2)
    #pragma unroll
    for (int nn = 0; nn < 2; ++nn) acc2[m2][nn] = (f32x4){0.f,0.f,0.f,0.f};
  #pragma unroll
  for (int hs = 0; hs < 4; ++hs){
    bf16x8 b2[2];
    #pragma unroll
    for (int nn = 0; nn < 2; ++nn)
      b2[nn] = *(const bf16x8*)&W2t[(nn*16 + l15)*HH + hs*32 + l4*8];
    #pragma unroll
    for (int m2 = 0; m2 < 2; ++m2){
      bf16x8 a2 = *(const bf16x8*)&smem[(w*32 + m2*16 + l15)*136 + hs*32 + l4*8];
      #pragma unroll
      for (int nn = 0; nn < 2; ++nn)
        acc2[m2][nn] = __builtin_amdgcn_mfma_f32_16x16x32_bf16(a2, b2[nn], acc2[m2][nn], 0,0,0);
    }
  }
  #pragma unroll
  for (int m2 = 0; m2 < 2; ++m2){
    #pragma unroll
    for (int nn = 0; nn < 2; ++nn){
      int cc = nn*16 + l15;
      if (cc < 30){
        float b2v = bd2[cc];
        #pragma unroll
        for (int r = 0; r < 4; ++r){
          int gp = w*32 + m2*16 + l4*4 + r;
          int gi = i0 + (gp >> 4), gj = j0 + (gp & 15);
          out[((long)gi*NN + gj)*30 + cc] = acc2[m2][nn][r] + b2v;
        }
      }
    }
  }
}

// ---------------- launch ----------------
extern "C" void kernel_launch(void* const* d_in, const int* in_sizes, int n_in,
                              void* d_out, int out_size, void* d_ws, size_t ws_size,
                              hipStream_t stream){
  const float* lm   = (const float*)d_in[0];
  const float* nf   = (const float*)d_in[1];
  const float* ef   = (const float*)d_in[2];
  const int*   src  = (const int*)d_in[3];
  const int*   dst  = (const int*)d_in[4];
  const int*   midx = (const int*)d_in[5];
  const float* Wg0  = (const float*)d_in[6];
  const float* bg0  = (const float*)d_in[7];
  const float* Wg1  = (const float*)d_in[8];
  const float* bg1  = (const float*)d_in[9];
  const float* Wd1  = (const float*)d_in[10];
  const float* bd1  = (const float*)d_in[11];
  const float* Wd2  = (const float*)d_in[12];
  const float* bd2  = (const float*)d_in[13];
  const float* Wm1  = (const float*)d_in[14];
  const float* bm1  = (const float*)d_in[15];
  const float* Wm2  = (const float*)d_in[16];
  const float* bm2  = (const float*)d_in[17];
  float* dis = (float*)d_out;

  char* ws = (char*)d_ws;
  size_t off = 0;
  auto alloc = [&](size_t bytes)->void*{
    void* p = ws + off; off += (bytes + 255) & ~(size_t)255; return p;
  };
  float* x0   = (float*)alloc((size_t)NN*DD*4);
  float* yb   = (float*)alloc((size_t)NN*DD*4);
  float* hb   = (float*)alloc((size_t)NN*DD*4);
  float* ew   = (float*)alloc((size_t)EE*4);
  int*   offs = (int*)alloc((NN+1)*4);
  int*   sorted = (int*)alloc(EE*4);
  short* WtAh = (short*)alloc((size_t)DD*DD*2);
  short* WtAl = (short*)alloc((size_t)DD*DD*2);
  short* W1t  = (short*)alloc((size_t)HH*DD*2);
  short* W2t  = (short*)alloc((size_t)32*HH*2);
  float* P    = (float*)alloc((size_t)4*NN*DD*4);

  k_prep<<<1402,512,0,stream>>>(lm, nf, x0, dst, ef, offs, sorted, ew,
                                Wd1, W1t, Wd2, W2t, Wg0, WtAh, WtAl);

  k_agg<<<dim3(384,5),256,0,stream>>>(x0, ew, src, offs, sorted, yb);
  k_gin_gemm<<<dim3(3,10,4),256,0,stream>>>(yb, WtAh, WtAl, P);
  k_red_t<<<880,256,0,stream>>>(P, bg0, nullptr, hb, Wg1, WtAh, WtAl);

  k_agg<<<dim3(384,5),256,0,stream>>>(hb, ew, src, offs, sorted, yb);
  k_gin_gemm<<<dim3(3,10,4),256,0,stream>>>(yb, WtAh, WtAl, P);
  k_red_t<<<480,256,0,stream>>>(P, bg1, x0, hb, nullptr, nullptr, nullptr);

  k_dis<<<1216,256,0,stream>>>(hb, W1t, bd1, W2t, bd2, dis,
                               midx, Wm1, bm1, Wm2, bm2);
}

// Round 5
// 203.244 us; speedup vs baseline: 2.0341x; 1.0109x over previous
//
#include <hip/hip_runtime.h>
#include <hip/hip_bf16.h>

#define NN 384
#define EE 12288
#define DD 1280
#define HH 128
#define DISROWS (NN*NN)

typedef short bf16x8 __attribute__((ext_vector_type(8)));
typedef short bf16x4 __attribute__((ext_vector_type(4)));
typedef float f32x4  __attribute__((ext_vector_type(4)));

__device__ __forceinline__ unsigned short f2bf(float x){
  unsigned u = __builtin_bit_cast(unsigned, x);
  u += 0x7fffu + ((u >> 16) & 1u);
  return (unsigned short)(u >> 16);
}
__device__ __forceinline__ float bf2f(unsigned short h){
  unsigned u = ((unsigned)h) << 16;
  return __builtin_bit_cast(float, u);
}
__device__ __forceinline__ short f2bf_fast(float x){
  return (short)__bfloat16_as_ushort(__float2bfloat16(x));
}
__device__ __forceinline__ void glds16(const short* g, short* l){
  __builtin_amdgcn_global_load_lds((const __attribute__((address_space(1))) void*)g,
                                   (__attribute__((address_space(3))) void*)l, 16, 0, 0);
}

// transpose W[R][C] -> Thi/Tlo[C][R] as bf16 hi (+ optional lo residual). 256 threads.
__device__ __forceinline__ void tsplit_body(const float* __restrict__ W,
                                            short* __restrict__ Thi, short* __restrict__ Tlo,
                                            int R, int C, int bx, int by, int t,
                                            float* tile /* [64][65] shared */){
  int rb = by*64, cb = bx*64;
  int r  = t >> 2;
  int cs = (t & 3) * 16;
  const float* sp = W + (long)(rb + r)*C + cb + cs;
  #pragma unroll
  for (int i = 0; i < 16; i += 4){
    f32x4 v = *(const f32x4*)(sp + i);
    tile[r*65 + cs+i+0] = v[0]; tile[r*65 + cs+i+1] = v[1];
    tile[r*65 + cs+i+2] = v[2]; tile[r*65 + cs+i+3] = v[3];
  }
  __syncthreads();
  int cp = t >> 2;
  int rs = (t & 3) * 16;
  bf16x8 vh0, vh1, vl0, vl1;
  #pragma unroll
  for (int i = 0; i < 8; ++i){
    float f = tile[(rs+i)*65 + cp];
    unsigned short h = f2bf(f);
    vh0[i] = (short)h; vl0[i] = (short)f2bf(f - bf2f(h));
  }
  #pragma unroll
  for (int i = 0; i < 8; ++i){
    float f = tile[(rs+8+i)*65 + cp];
    unsigned short h = f2bf(f);
    vh1[i] = (short)h; vl1[i] = (short)f2bf(f - bf2f(h));
  }
  long ob = (long)(cb + cp)*R + rb + rs;
  *(bf16x8*)&Thi[ob]   = vh0;
  *(bf16x8*)&Thi[ob+8] = vh1;
  if (Tlo){
    *(bf16x8*)&Tlo[ob]   = vl0;
    *(bf16x8*)&Tlo[ob+8] = vl1;
  }
}

// ---------------- mega-prep (512 thr): feat | graph CSR | Wd prep | tsplit(Wg0) ----------------
// blocks: [0,960) feat; [960] graph; [961,1002) dw; [1002,1402) tsplit Wg0
__global__ void k_prep(const float* __restrict__ lm, const float* __restrict__ nf,
                       float* __restrict__ x0,
                       const int* __restrict__ dst, const float* __restrict__ ef,
                       int* __restrict__ offs, int* __restrict__ sorted,
                       float* __restrict__ ew,
                       const float* __restrict__ Wd1, short* __restrict__ W1t,
                       const float* __restrict__ Wd2, short* __restrict__ W2t,
                       const float* __restrict__ Wg0, short* __restrict__ WtAh,
                       short* __restrict__ WtAl){
  __shared__ __align__(16) float sh[64*65];
  const int b = blockIdx.x;
  const int t = threadIdx.x;  // 512
  if (b < 960){
    int i = b*512 + t;
    int n = i / 1280;
    int d = i - n*1280;
    x0[i] = (d < 1024) ? lm[(n+1)*1024 + d] : nf[n*256 + (d-1024)];
    return;
  }
  if (b == 960){
    int* cnt = (int*)sh;
    int* base = cnt + 512;
    if (t < 512) cnt[t] = 0;
    __syncthreads();
    for (int e = t; e < EE; e += 512){
      atomicAdd(&cnt[dst[e]], 1);
      float f = ef[e];
      ew[e] = 1.0f/(f*f + 1e-6f);
    }
    __syncthreads();
    for (int off = 1; off < 512; off <<= 1){
      int v = (t >= off) ? cnt[t - off] : 0;
      __syncthreads();
      cnt[t] += v;
      __syncthreads();
    }
    if (t < NN){
      int excl = t ? cnt[t-1] : 0;
      offs[t] = excl;
      base[t] = excl;
    }
    if (t == 0) offs[NN] = EE;
    __syncthreads();
    for (int e = t; e < EE; e += 512){
      int p = atomicAdd(&base[dst[e]], 1);
      sorted[p] = e;
    }
    return;
  }
  if (b < 1002){
    int g = b - 961;
    if (g < 40){
      if (t < 256) tsplit_body(Wd1, W1t, nullptr, DD, HH, g & 1, g >> 1, t, sh);
      else { __syncthreads(); }
      return;
    }
    for (int i = t; i < 32*HH; i += 512){
      int c = i >> 7, h = i & 127;
      float v = (c < 30) ? Wd2[h*30 + c] : 0.f;
      W2t[i] = (short)f2bf(v);
    }
    return;
  }
  {
    int g = b - 1002;
    if (t < 256) tsplit_body(Wg0, WtAh, WtAl, DD, DD, g % 20, g / 20, t, sh);
    else { __syncthreads(); }
  }
}

// ---------------- edge aggregation ----------------
__global__ void k_agg(const float* __restrict__ X, const float* __restrict__ ew,
                      const int* __restrict__ src, const int* __restrict__ offs,
                      const int* __restrict__ sorted, float* __restrict__ Y){
  __shared__ int   s_off[160];
  __shared__ float s_w[160];
  const int v = blockIdx.x;
  const int d = blockIdx.y*256 + threadIdx.x;
  const int t = threadIdx.x;
  float acc = X[(long)v*DD + d];
  const int b = offs[v], e = offs[v+1];
  for (int c0 = b; c0 < e; c0 += 160){
    int n = e - c0; if (n > 160) n = 160;
    __syncthreads();
    if (t < n){
      int eid = sorted[c0 + t];
      s_off[t] = src[eid]*DD;
      s_w[t]   = ew[eid];
    }
    __syncthreads();
    int k = 0;
    for (; k + 4 <= n; k += 4){
      acc += s_w[k]  *X[s_off[k]   + d];
      acc += s_w[k+1]*X[s_off[k+1] + d];
      acc += s_w[k+2]*X[s_off[k+2] + d];
      acc += s_w[k+3]*X[s_off[k+3] + d];
    }
    for (; k < n; ++k) acc += s_w[k]*X[s_off[k] + d];
  }
  Y[(long)v*DD + d] = acc;
}

// ---------------- GIN GEMM, split-K=4 ----------------
__launch_bounds__(256, 2)
__global__ void k_gin_gemm(const float* __restrict__ Y, const short* __restrict__ Whi,
                           const short* __restrict__ Wlo, float* __restrict__ P){
  __shared__ __align__(16) short Ahi[128*40], Alo[128*40], Bhi[128*40], Blo[128*40];
  const int m0 = blockIdx.x*128;
  const int n0 = blockIdx.y*128;
  const int kbase = blockIdx.z*320;
  const int t = threadIdx.x, w = t >> 6, lane = t & 63;
  const int l15 = lane & 15, l4 = lane >> 4;
  f32x4 acc[2][8];
  #pragma unroll
  for (int m = 0; m < 2; ++m)
    #pragma unroll
    for (int n = 0; n < 8; ++n) acc[m][n] = (f32x4){0.f,0.f,0.f,0.f};

  const int row = t >> 1, half = t & 1;
  const float* ap  = Y   + (long)(m0+row)*DD + half*16;
  const short* bph = Whi + (long)(n0+row)*DD + half*16;
  const short* bpl = Wlo + (long)(n0+row)*DD + half*16;

  for (int kk = 0; kk < 10; ++kk){
    int d0 = kbase + kk*32;
    __syncthreads();
    #pragma unroll
    for (int g = 0; g < 2; ++g){
      f32x4 v0 = *(const f32x4*)(ap + d0 + g*8);
      f32x4 v1 = *(const f32x4*)(ap + d0 + g*8 + 4);
      bf16x8 vh, vl;
      #pragma unroll
      for (int q = 0; q < 4; ++q){
        unsigned short h0 = f2bf(v0[q]);
        vh[q]   = (short)h0; vl[q]   = (short)f2bf(v0[q] - bf2f(h0));
        unsigned short h1 = f2bf(v1[q]);
        vh[4+q] = (short)h1; vl[4+q] = (short)f2bf(v1[q] - bf2f(h1));
      }
      *(bf16x8*)&Ahi[row*40 + half*16 + g*8] = vh;
      *(bf16x8*)&Alo[row*40 + half*16 + g*8] = vl;
    }
    *(bf16x8*)&Bhi[row*40 + half*16]     = *(const bf16x8*)(bph + d0);
    *(bf16x8*)&Bhi[row*40 + half*16 + 8] = *(const bf16x8*)(bph + d0 + 8);
    *(bf16x8*)&Blo[row*40 + half*16]     = *(const bf16x8*)(bpl + d0);
    *(bf16x8*)&Blo[row*40 + half*16 + 8] = *(const bf16x8*)(bpl + d0 + 8);
    __syncthreads();

    bf16x8 ah[2], al[2];
    #pragma unroll
    for (int m = 0; m < 2; ++m){
      int rr = w*32 + m*16 + l15;
      ah[m] = *(const bf16x8*)&Ahi[rr*40 + l4*8];
      al[m] = *(const bf16x8*)&Alo[rr*40 + l4*8];
    }
    #pragma unroll
    for (int n = 0; n < 8; ++n){
      int rr = n*16 + l15;
      bf16x8 bh = *(const bf16x8*)&Bhi[rr*40 + l4*8];
      bf16x8 bl = *(const bf16x8*)&Blo[rr*40 + l4*8];
      #pragma unroll
      for (int m = 0; m < 2; ++m){
        acc[m][n] = __builtin_amdgcn_mfma_f32_16x16x32_bf16(ah[m], bh, acc[m][n], 0,0,0);
        acc[m][n] = __builtin_amdgcn_mfma_f32_16x16x32_bf16(ah[m], bl, acc[m][n], 0,0,0);
        acc[m][n] = __builtin_amdgcn_mfma_f32_16x16x32_bf16(al[m], bh, acc[m][n], 0,0,0);
      }
    }
  }
  float* Pz = P + (long)blockIdx.z*NN*DD;
  #pragma unroll
  for (int m = 0; m < 2; ++m){
    #pragma unroll
    for (int n = 0; n < 8; ++n){
      int gr0 = m0 + w*32 + m*16 + l4*4;
      int gc  = n0 + n*16 + l15;
      #pragma unroll
      for (int r = 0; r < 4; ++r)
        Pz[(long)(gr0+r)*DD + gc] = acc[m][n][r];
    }
  }
}

// red: blocks [0,480) sum P + bias (+resid) -> Out; blocks [480,880): tsplit(Wg1) -> WtA
__global__ void k_red_t(const float* __restrict__ P, const float* __restrict__ bias,
                        const float* __restrict__ resid, float* __restrict__ Out,
                        const float* __restrict__ Wg1, short* __restrict__ WtAh,
                        short* __restrict__ WtAl){
  __shared__ __align__(16) float sh[64*65];
  const int b = blockIdx.x;
  if (b >= 480){
    if (Wg1){
      int g = b - 480;
      tsplit_body(Wg1, WtAh, WtAl, DD, DD, g % 20, g / 20, threadIdx.x, sh);
    }
    return;
  }
  const int i = b*256 + threadIdx.x;
  const int col = (i*4) % DD;
  const f32x4* P4 = (const f32x4*)P;
  f32x4 s = P4[i];
  s += P4[i + 122880];
  s += P4[i + 2*122880];
  s += P4[i + 3*122880];
  s += *(const f32x4*)(bias + col);
  if (resid) s += ((const f32x4*)resid)[i];
  ((f32x4*)Out)[i] = s;
}

// ---------------- fused dis MLP v5 (triangular) + mask head ----------------
// blocks [0,300): upper-triangle 16x16 tiles, 512 thr / 8 waves.
// Main loop: macro-K=128, W tile via global_load_lds with pre-swizzled global addr
// (XOR slot^(h&7)), LDS linear [h][128k], 1 barrier per macro.
// MFMA called as mfma(Wfrag, Sqfrag, acc): acc rows = h (l4*4+r), cols = j (l15).
// Epilogue: TL[pair][136] written with b64 packed bf16x4 (4 consecutive h per lane).
// blocks [300,364): mask head, node b-300.
__launch_bounds__(512, 4)
__global__ void k_dis(const float* __restrict__ X, const short* __restrict__ W1t,
                      const float* __restrict__ bd1, const short* __restrict__ W2t,
                      const float* __restrict__ bd2, float* __restrict__ out,
                      const int* __restrict__ midx,
                      const float* __restrict__ Wm1, const float* __restrict__ bm1,
                      const float* __restrict__ Wm2, const float* __restrict__ bm2){
  __shared__ __align__(16) short smem[32768];   // 65536 B: W dbuf 2x32KB; TL alias
  const int b = blockIdx.x;
  const int t = threadIdx.x;

  if (b >= 300){
    // ---- mask head ----
    float* tl = (float*)smem;
    int m = b - 300;
    if (t < HH){
      const float* x = X + (long)midx[m]*DD;
      float a0 = 0.f, a1 = 0.f, a2 = 0.f, a3 = 0.f;
      for (int d = 0; d < DD; d += 4){
        a0 += x[d]   * Wm1[(d)*HH + t];
        a1 += x[d+1] * Wm1[(d+1)*HH + t];
        a2 += x[d+2] * Wm1[(d+2)*HH + t];
        a3 += x[d+3] * Wm1[(d+3)*HH + t];
      }
      float v = a0 + a1 + a2 + a3 + bm1[t];
      tl[t] = v > 0.f ? v : 0.f;
    }
    __syncthreads();
    if (t < 2){
      float s = bm2[t];
      for (int h = 0; h < HH; ++h) s += tl[h]*Wm2[h*2 + t];
      out[(long)DISROWS*30 + m*2 + t] = tanhf(s);
    }
    return;
  }

  // triangular unrank: row ib has (24-ib) tiles
  int ib = 0, rem = b;
  while (rem >= 24 - ib){ rem -= 24 - ib; ++ib; }
  const int jb = ib + rem;
  const int i0 = ib*16, j0 = jb*16;

  const int w = t >> 6, lane = t & 63;
  const int l15 = lane & 15, l4 = lane >> 4;

  f32x4 acc[2][8];
  #pragma unroll
  for (int m = 0; m < 2; ++m)
    #pragma unroll
    for (int n = 0; n < 8; ++n) acc[m][n] = (f32x4){0.f,0.f,0.f,0.f};

  // X pointers (direct global, register prefetch)
  const float* xj_p  = X + (long)(j0 + l15)*DD + l4*8;
  const float* xi_p0 = X + (long)(i0 + 2*w)*DD + l4*8;
  const float* xi_p1 = xi_p0 + DD;

  // W global_load_lds: wave w stages h rows [w*16, w*16+16), 4 insts x 1KB.
  // lane -> h = w*16 + i*4 + l4, slot = l15; global addr inverse-swizzled.
  const short* wg[4];
  #pragma unroll
  for (int i = 0; i < 4; ++i){
    int h = w*16 + i*4 + l4;
    wg[i] = W1t + (long)h*DD + ((l15 ^ (h & 7))*8);
  }

  // prologue: macro 0 -> buf0; X regs for d=0
  #pragma unroll
  for (int i = 0; i < 4; ++i)
    glds16(wg[i], &smem[(w*16 + i*4)*128]);
  f32x4 xj0 = *(const f32x4*)(xj_p);
  f32x4 xj1 = *(const f32x4*)(xj_p + 4);
  f32x4 xA0 = *(const f32x4*)(xi_p0);
  f32x4 xA1 = *(const f32x4*)(xi_p0 + 4);
  f32x4 xB0 = *(const f32x4*)(xi_p1);
  f32x4 xB1 = *(const f32x4*)(xi_p1 + 4);
  __syncthreads();   // drains vmcnt -> buf0 ready

  for (int mk = 0; mk < 10; ++mk){
    const int cur = (mk & 1) << 14;       // *16384 shorts
    const int nxt = cur ^ 16384;
    if (mk < 9){
      #pragma unroll
      for (int i = 0; i < 4; ++i)
        glds16(wg[i] + (mk+1)*128, &smem[nxt + (w*16 + i*4)*128]);
    }
    #pragma unroll
    for (int ks = 0; ks < 4; ++ks){
      // Sq fragments (B-operand: l15 = j, l4*8 = k)
      bf16x8 a0, a1;
      #pragma unroll
      for (int q = 0; q < 4; ++q){
        float d0 = xj0[q]-xA0[q]; a0[q]   = f2bf_fast(d0*d0);
        float d1 = xj1[q]-xA1[q]; a0[4+q] = f2bf_fast(d1*d1);
        float d2 = xj0[q]-xB0[q]; a1[q]   = f2bf_fast(d2*d2);
        float d3 = xj1[q]-xB1[q]; a1[4+q] = f2bf_fast(d3*d3);
      }
      const int step = mk*4 + ks;
      if (step < 39){
        const int d1 = (step+1)*32;
        xj0 = *(const f32x4*)(xj_p + d1);  xj1 = *(const f32x4*)(xj_p + d1 + 4);
        xA0 = *(const f32x4*)(xi_p0 + d1); xA1 = *(const f32x4*)(xi_p0 + d1 + 4);
        xB0 = *(const f32x4*)(xi_p1 + d1); xB1 = *(const f32x4*)(xi_p1 + d1 + 4);
      }
      const int rb = cur + l15*128 + (((ks*4 + l4) ^ (l15 & 7))*8);
      #pragma unroll
      for (int n = 0; n < 8; ++n){
        bf16x8 wf = *(const bf16x8*)&smem[rb + n*2048];
        acc[0][n] = __builtin_amdgcn_mfma_f32_16x16x32_bf16(wf, a0, acc[0][n], 0,0,0);
        acc[1][n] = __builtin_amdgcn_mfma_f32_16x16x32_bf16(wf, a1, acc[1][n], 0,0,0);
      }
    }
    __syncthreads();
  }

  // ---- layer 2 in two chunks of 128 pairs; TL[pair][136] aliases smem ----
  f32x4 bd1v[8];
  #pragma unroll
  for (int n = 0; n < 8; ++n) bd1v[n] = *(const f32x4*)(bd1 + n*16 + l4*4);

  #pragma unroll
  for (int c = 0; c < 2; ++c){
    if ((w >> 2) == c){
      #pragma unroll
      for (int ii = 0; ii < 2; ++ii){
        int lp = (2*w + ii - c*8)*16 + l15;
        #pragma unroll
        for (int n = 0; n < 8; ++n){
          bf16x4 pv;
          #pragma unroll
          for (int r = 0; r < 4; ++r){
            float v = acc[ii][n][r] + bd1v[n][r];
            v = v > 0.f ? v : 0.f;
            pv[r] = f2bf_fast(v);
          }
          *(bf16x4*)&smem[lp*136 + n*16 + l4*4] = pv;
        }
      }
    }
    __syncthreads();

    f32x4 acc2[2];
    acc2[0] = (f32x4){0.f,0.f,0.f,0.f};
    acc2[1] = (f32x4){0.f,0.f,0.f,0.f};
    #pragma unroll
    for (int hs = 0; hs < 4; ++hs){
      bf16x8 a2 = *(const bf16x8*)&smem[(w*16 + l15)*136 + hs*32 + l4*8];
      #pragma unroll
      for (int nn = 0; nn < 2; ++nn){
        bf16x8 b2 = *(const bf16x8*)&W2t[(nn*16 + l15)*HH + hs*32 + l4*8];
        acc2[nn] = __builtin_amdgcn_mfma_f32_16x16x32_bf16(a2, b2, acc2[nn], 0,0,0);
      }
    }
    #pragma unroll
    for (int nn = 0; nn < 2; ++nn){
      int cc = nn*16 + l15;
      if (cc < 30){
        float b2v = bd2[cc];
        #pragma unroll
        for (int r = 0; r < 4; ++r){
          int gp = c*128 + w*16 + l4*4 + r;
          int gi = i0 + (gp >> 4), gj = j0 + (gp & 15);
          float v = acc2[nn][r] + b2v;
          out[((long)gi*NN + gj)*30 + cc] = v;
          if (ib != jb) out[((long)gj*NN + gi)*30 + cc] = v;
        }
      }
    }
    if (c == 0) __syncthreads();
  }
}

// ---------------- launch ----------------
extern "C" void kernel_launch(void* const* d_in, const int* in_sizes, int n_in,
                              void* d_out, int out_size, void* d_ws, size_t ws_size,
                              hipStream_t stream){
  const float* lm   = (const float*)d_in[0];
  const float* nf   = (const float*)d_in[1];
  const float* ef   = (const float*)d_in[2];
  const int*   src  = (const int*)d_in[3];
  const int*   dst  = (const int*)d_in[4];
  const int*   midx = (const int*)d_in[5];
  const float* Wg0  = (const float*)d_in[6];
  const float* bg0  = (const float*)d_in[7];
  const float* Wg1  = (const float*)d_in[8];
  const float* bg1  = (const float*)d_in[9];
  const float* Wd1  = (const float*)d_in[10];
  const float* bd1  = (const float*)d_in[11];
  const float* Wd2  = (const float*)d_in[12];
  const float* bd2  = (const float*)d_in[13];
  const float* Wm1  = (const float*)d_in[14];
  const float* bm1  = (const float*)d_in[15];
  const float* Wm2  = (const float*)d_in[16];
  const float* bm2  = (const float*)d_in[17];
  float* dis = (float*)d_out;

  char* ws = (char*)d_ws;
  size_t off = 0;
  auto alloc = [&](size_t bytes)->void*{
    void* p = ws + off; off += (bytes + 255) & ~(size_t)255; return p;
  };
  float* x0   = (float*)alloc((size_t)NN*DD*4);
  float* yb   = (float*)alloc((size_t)NN*DD*4);
  float* hb   = (float*)alloc((size_t)NN*DD*4);
  float* ew   = (float*)alloc((size_t)EE*4);
  int*   offs = (int*)alloc((NN+1)*4);
  int*   sorted = (int*)alloc(EE*4);
  short* WtAh = (short*)alloc((size_t)DD*DD*2);
  short* WtAl = (short*)alloc((size_t)DD*DD*2);
  short* W1t  = (short*)alloc((size_t)HH*DD*2);
  short* W2t  = (short*)alloc((size_t)32*HH*2);
  float* P    = (float*)alloc((size_t)4*NN*DD*4);

  k_prep<<<1402,512,0,stream>>>(lm, nf, x0, dst, ef, offs, sorted, ew,
                                Wd1, W1t, Wd2, W2t, Wg0, WtAh, WtAl);

  k_agg<<<dim3(384,5),256,0,stream>>>(x0, ew, src, offs, sorted, yb);
  k_gin_gemm<<<dim3(3,10,4),256,0,stream>>>(yb, WtAh, WtAl, P);
  k_red_t<<<880,256,0,stream>>>(P, bg0, nullptr, hb, Wg1, WtAh, WtAl);

  k_agg<<<dim3(384,5),256,0,stream>>>(hb, ew, src, offs, sorted, yb);
  k_gin_gemm<<<dim3(3,10,4),256,0,stream>>>(yb, WtAh, WtAl, P);
  k_red_t<<<480,256,0,stream>>>(P, bg1, x0, hb, nullptr, nullptr, nullptr);

  k_dis<<<364,512,0,stream>>>(hb, W1t, bd1, W2t, bd2, dis,
                              midx, Wm1, bm1, Wm2, bm2);
}

// Round 6
// 142.283 us; speedup vs baseline: 2.9057x; 1.4285x over previous
//
#include <hip/hip_runtime.h>
#include <hip/hip_bf16.h>

#define NN 384
#define EE 12288
#define DD 1280
#define HH 128
#define DISROWS (NN*NN)

typedef short bf16x8 __attribute__((ext_vector_type(8)));
typedef short bf16x4 __attribute__((ext_vector_type(4)));
typedef float f32x4  __attribute__((ext_vector_type(4)));

__device__ __forceinline__ unsigned short f2bf(float x){
  unsigned u = __builtin_bit_cast(unsigned, x);
  u += 0x7fffu + ((u >> 16) & 1u);
  return (unsigned short)(u >> 16);
}
__device__ __forceinline__ float bf2f(unsigned short h){
  unsigned u = ((unsigned)h) << 16;
  return __builtin_bit_cast(float, u);
}
__device__ __forceinline__ short f2bf_fast(float x){
  return (short)__bfloat16_as_ushort(__float2bfloat16(x));
}
__device__ __forceinline__ void glds16(const short* g, short* l){
  __builtin_amdgcn_global_load_lds((const __attribute__((address_space(1))) void*)g,
                                   (__attribute__((address_space(3))) void*)l, 16, 0, 0);
}

// transpose W[R][C] -> Thi/Tlo[C][R] as bf16 hi (+ optional lo residual). 256 threads.
__device__ __forceinline__ void tsplit_body(const float* __restrict__ W,
                                            short* __restrict__ Thi, short* __restrict__ Tlo,
                                            int R, int C, int bx, int by, int t,
                                            float* tile /* [64][65] shared */){
  int rb = by*64, cb = bx*64;
  int r  = t >> 2;
  int cs = (t & 3) * 16;
  const float* sp = W + (long)(rb + r)*C + cb + cs;
  #pragma unroll
  for (int i = 0; i < 16; i += 4){
    f32x4 v = *(const f32x4*)(sp + i);
    tile[r*65 + cs+i+0] = v[0]; tile[r*65 + cs+i+1] = v[1];
    tile[r*65 + cs+i+2] = v[2]; tile[r*65 + cs+i+3] = v[3];
  }
  __syncthreads();
  int cp = t >> 2;
  int rs = (t & 3) * 16;
  bf16x8 vh0, vh1, vl0, vl1;
  #pragma unroll
  for (int i = 0; i < 8; ++i){
    float f = tile[(rs+i)*65 + cp];
    unsigned short h = f2bf(f);
    vh0[i] = (short)h; vl0[i] = (short)f2bf(f - bf2f(h));
  }
  #pragma unroll
  for (int i = 0; i < 8; ++i){
    float f = tile[(rs+8+i)*65 + cp];
    unsigned short h = f2bf(f);
    vh1[i] = (short)h; vl1[i] = (short)f2bf(f - bf2f(h));
  }
  long ob = (long)(cb + cp)*R + rb + rs;
  *(bf16x8*)&Thi[ob]   = vh0;
  *(bf16x8*)&Thi[ob+8] = vh1;
  if (Tlo){
    *(bf16x8*)&Tlo[ob]   = vl0;
    *(bf16x8*)&Tlo[ob+8] = vl1;
  }
}

// ---------------- mega-prep (512 thr): feat | graph CSR | Wd prep | tsplit(Wg0) ----------------
// blocks: [0,960) feat; [960] graph; [961,1002) dw; [1002,1402) tsplit Wg0
__global__ void k_prep(const float* __restrict__ lm, const float* __restrict__ nf,
                       float* __restrict__ x0,
                       const int* __restrict__ dst, const float* __restrict__ ef,
                       int* __restrict__ offs, int* __restrict__ sorted,
                       float* __restrict__ ew,
                       const float* __restrict__ Wd1, short* __restrict__ W1t,
                       const float* __restrict__ Wd2, short* __restrict__ W2t,
                       const float* __restrict__ Wg0, short* __restrict__ WtAh,
                       short* __restrict__ WtAl){
  __shared__ __align__(16) float sh[64*65];
  const int b = blockIdx.x;
  const int t = threadIdx.x;  // 512
  if (b < 960){
    int i = b*512 + t;
    int n = i / 1280;
    int d = i - n*1280;
    x0[i] = (d < 1024) ? lm[(n+1)*1024 + d] : nf[n*256 + (d-1024)];
    return;
  }
  if (b == 960){
    int* cnt = (int*)sh;
    int* base = cnt + 512;
    if (t < 512) cnt[t] = 0;
    __syncthreads();
    for (int e = t; e < EE; e += 512){
      atomicAdd(&cnt[dst[e]], 1);
      float f = ef[e];
      ew[e] = 1.0f/(f*f + 1e-6f);
    }
    __syncthreads();
    for (int off = 1; off < 512; off <<= 1){
      int v = (t >= off) ? cnt[t - off] : 0;
      __syncthreads();
      cnt[t] += v;
      __syncthreads();
    }
    if (t < NN){
      int excl = t ? cnt[t-1] : 0;
      offs[t] = excl;
      base[t] = excl;
    }
    if (t == 0) offs[NN] = EE;
    __syncthreads();
    for (int e = t; e < EE; e += 512){
      int p = atomicAdd(&base[dst[e]], 1);
      sorted[p] = e;
    }
    return;
  }
  if (b < 1002){
    int g = b - 961;
    if (g < 40){
      if (t < 256) tsplit_body(Wd1, W1t, nullptr, DD, HH, g & 1, g >> 1, t, sh);
      else { __syncthreads(); }
      return;
    }
    for (int i = t; i < 32*HH; i += 512){
      int c = i >> 7, h = i & 127;
      float v = (c < 30) ? Wd2[h*30 + c] : 0.f;
      W2t[i] = (short)f2bf(v);
    }
    return;
  }
  {
    int g = b - 1002;
    if (t < 256) tsplit_body(Wg0, WtAh, WtAl, DD, DD, g % 20, g / 20, t, sh);
    else { __syncthreads(); }
  }
}

// ---------------- edge aggregation ----------------
__global__ void k_agg(const float* __restrict__ X, const float* __restrict__ ew,
                      const int* __restrict__ src, const int* __restrict__ offs,
                      const int* __restrict__ sorted, float* __restrict__ Y){
  __shared__ int   s_off[160];
  __shared__ float s_w[160];
  const int v = blockIdx.x;
  const int d = blockIdx.y*256 + threadIdx.x;
  const int t = threadIdx.x;
  float acc = X[(long)v*DD + d];
  const int b = offs[v], e = offs[v+1];
  for (int c0 = b; c0 < e; c0 += 160){
    int n = e - c0; if (n > 160) n = 160;
    __syncthreads();
    if (t < n){
      int eid = sorted[c0 + t];
      s_off[t] = src[eid]*DD;
      s_w[t]   = ew[eid];
    }
    __syncthreads();
    int k = 0;
    for (; k + 4 <= n; k += 4){
      acc += s_w[k]  *X[s_off[k]   + d];
      acc += s_w[k+1]*X[s_off[k+1] + d];
      acc += s_w[k+2]*X[s_off[k+2] + d];
      acc += s_w[k+3]*X[s_off[k+3] + d];
    }
    for (; k < n; ++k) acc += s_w[k]*X[s_off[k] + d];
  }
  Y[(long)v*DD + d] = acc;
}

// ---------------- GIN GEMM, split-K=4 ----------------
__launch_bounds__(256, 2)
__global__ void k_gin_gemm(const float* __restrict__ Y, const short* __restrict__ Whi,
                           const short* __restrict__ Wlo, float* __restrict__ P){
  __shared__ __align__(16) short Ahi[128*40], Alo[128*40], Bhi[128*40], Blo[128*40];
  const int m0 = blockIdx.x*128;
  const int n0 = blockIdx.y*128;
  const int kbase = blockIdx.z*320;
  const int t = threadIdx.x, w = t >> 6, lane = t & 63;
  const int l15 = lane & 15, l4 = lane >> 4;
  f32x4 acc[2][8];
  #pragma unroll
  for (int m = 0; m < 2; ++m)
    #pragma unroll
    for (int n = 0; n < 8; ++n) acc[m][n] = (f32x4){0.f,0.f,0.f,0.f};

  const int row = t >> 1, half = t & 1;
  const float* ap  = Y   + (long)(m0+row)*DD + half*16;
  const short* bph = Whi + (long)(n0+row)*DD + half*16;
  const short* bpl = Wlo + (long)(n0+row)*DD + half*16;

  for (int kk = 0; kk < 10; ++kk){
    int d0 = kbase + kk*32;
    __syncthreads();
    #pragma unroll
    for (int g = 0; g < 2; ++g){
      f32x4 v0 = *(const f32x4*)(ap + d0 + g*8);
      f32x4 v1 = *(const f32x4*)(ap + d0 + g*8 + 4);
      bf16x8 vh, vl;
      #pragma unroll
      for (int q = 0; q < 4; ++q){
        unsigned short h0 = f2bf(v0[q]);
        vh[q]   = (short)h0; vl[q]   = (short)f2bf(v0[q] - bf2f(h0));
        unsigned short h1 = f2bf(v1[q]);
        vh[4+q] = (short)h1; vl[4+q] = (short)f2bf(v1[q] - bf2f(h1));
      }
      *(bf16x8*)&Ahi[row*40 + half*16 + g*8] = vh;
      *(bf16x8*)&Alo[row*40 + half*16 + g*8] = vl;
    }
    *(bf16x8*)&Bhi[row*40 + half*16]     = *(const bf16x8*)(bph + d0);
    *(bf16x8*)&Bhi[row*40 + half*16 + 8] = *(const bf16x8*)(bph + d0 + 8);
    *(bf16x8*)&Blo[row*40 + half*16]     = *(const bf16x8*)(bpl + d0);
    *(bf16x8*)&Blo[row*40 + half*16 + 8] = *(const bf16x8*)(bpl + d0 + 8);
    __syncthreads();

    bf16x8 ah[2], al[2];
    #pragma unroll
    for (int m = 0; m < 2; ++m){
      int rr = w*32 + m*16 + l15;
      ah[m] = *(const bf16x8*)&Ahi[rr*40 + l4*8];
      al[m] = *(const bf16x8*)&Alo[rr*40 + l4*8];
    }
    #pragma unroll
    for (int n = 0; n < 8; ++n){
      int rr = n*16 + l15;
      bf16x8 bh = *(const bf16x8*)&Bhi[rr*40 + l4*8];
      bf16x8 bl = *(const bf16x8*)&Blo[rr*40 + l4*8];
      #pragma unroll
      for (int m = 0; m < 2; ++m){
        acc[m][n] = __builtin_amdgcn_mfma_f32_16x16x32_bf16(ah[m], bh, acc[m][n], 0,0,0);
        acc[m][n] = __builtin_amdgcn_mfma_f32_16x16x32_bf16(ah[m], bl, acc[m][n], 0,0,0);
        acc[m][n] = __builtin_amdgcn_mfma_f32_16x16x32_bf16(al[m], bh, acc[m][n], 0,0,0);
      }
    }
  }
  float* Pz = P + (long)blockIdx.z*NN*DD;
  #pragma unroll
  for (int m = 0; m < 2; ++m){
    #pragma unroll
    for (int n = 0; n < 8; ++n){
      int gr0 = m0 + w*32 + m*16 + l4*4;
      int gc  = n0 + n*16 + l15;
      #pragma unroll
      for (int r = 0; r < 4; ++r)
        Pz[(long)(gr0+r)*DD + gc] = acc[m][n][r];
    }
  }
}

// red: blocks [0,480) sum P + bias (+resid) -> Out; blocks [480,880): tsplit(Wg1) -> WtA
__global__ void k_red_t(const float* __restrict__ P, const float* __restrict__ bias,
                        const float* __restrict__ resid, float* __restrict__ Out,
                        const float* __restrict__ Wg1, short* __restrict__ WtAh,
                        short* __restrict__ WtAl){
  __shared__ __align__(16) float sh[64*65];
  const int b = blockIdx.x;
  if (b >= 480){
    if (Wg1){
      int g = b - 480;
      tsplit_body(Wg1, WtAh, WtAl, DD, DD, g % 20, g / 20, threadIdx.x, sh);
    }
    return;
  }
  const int i = b*256 + threadIdx.x;
  const int col = (i*4) % DD;
  const f32x4* P4 = (const f32x4*)P;
  f32x4 s = P4[i];
  s += P4[i + 122880];
  s += P4[i + 2*122880];
  s += P4[i + 3*122880];
  s += *(const f32x4*)(bias + col);
  if (resid) s += ((const f32x4*)resid)[i];
  ((f32x4*)Out)[i] = s;
}

// ---------------- fused dis MLP v6 (triangular 8x16 tiles) + mask head ----------------
// blocks [0,600): tile (ib: 8 i-rows, jb: 16 j-cols), jb_min = ib>>1. 256 thr / 4 waves.
// Main loop: 20 macros of K=64. W [128h][64k] via glds16 (inverse-XOR-swizzled source,
// conflict-free b128 reads). X [24 rows][68] f32 reg-staged coalesced. 1 barrier/macro.
// Output: mfma(Wf, Sqf): rows=h, cols=j. Layer-2 via TL[pair][136]; all global writes
// staged in OT[128 pairs][30] f32 then written COALESCED (normal rows 480-f32 runs,
// mirror rows 240-f32 runs). Diagonal-overlap duplicates are bitwise identical.
// blocks [600,664): mask head.
__launch_bounds__(256, 3)
__global__ void k_dis(const float* __restrict__ X, const short* __restrict__ W1t,
                      const float* __restrict__ bd1, const short* __restrict__ W2t,
                      const float* __restrict__ bd2, float* __restrict__ out,
                      const int* __restrict__ midx,
                      const float* __restrict__ Wm1, const float* __restrict__ bm1,
                      const float* __restrict__ Wm2, const float* __restrict__ bm2){
  __shared__ __align__(16) short smem[25088];   // 50176 B
  const int b = blockIdx.x;
  const int t = threadIdx.x;

  if (b >= 600){
    // ---- mask head ----
    float* tl = (float*)smem;
    int m = b - 600;
    if (t < HH){
      const float* x = X + (long)midx[m]*DD;
      float a0 = 0.f, a1 = 0.f, a2 = 0.f, a3 = 0.f;
      for (int d = 0; d < DD; d += 4){
        a0 += x[d]   * Wm1[(d)*HH + t];
        a1 += x[d+1] * Wm1[(d+1)*HH + t];
        a2 += x[d+2] * Wm1[(d+2)*HH + t];
        a3 += x[d+3] * Wm1[(d+3)*HH + t];
      }
      float v = a0 + a1 + a2 + a3 + bm1[t];
      tl[t] = v > 0.f ? v : 0.f;
    }
    __syncthreads();
    if (t < 2){
      float s = bm2[t];
      for (int h = 0; h < HH; ++h) s += tl[h]*Wm2[h*2 + t];
      out[(long)DISROWS*30 + m*2 + t] = tanhf(s);
    }
    return;
  }

  // triangular unrank: ib pairs (2k,2k+1) each have 24-k tiles
  int k = 0, rem = b;
  while (rem >= 2*(24 - k)){ rem -= 2*(24 - k); ++k; }
  int ib = 2*k;
  if (rem >= 24 - k){ ++ib; rem -= 24 - k; }
  const int jb = k + rem;
  const int i0 = ib*8, j0 = jb*16;

  const int w = t >> 6, lane = t & 63;
  const int l15 = lane & 15, l4 = lane >> 4;

  short* WA = smem;                       // [2][128][64] shorts (32768 B)
  float* XF = (float*)(smem + 16384);     // [2][24][68] f32 (13056 B)
  short* TL = smem;                       // alias: [128][136] shorts (34816 B)
  float* OT = (float*)(smem + 17408);     // alias: [128][30] f32 (15360 B)

  f32x4 acc[2][8];
  #pragma unroll
  for (int m = 0; m < 2; ++m)
    #pragma unroll
    for (int n = 0; n < 8; ++n) acc[m][n] = (f32x4){0.f,0.f,0.f,0.f};

  // W staging: wave w, inst i covers h rows [w*32+i*8, +8); lane -> h += lane>>3, slot lane&7
  const short* wsrc[4];
  #pragma unroll
  for (int i = 0; i < 4; ++i){
    int hb = w*32 + i*8 + (lane >> 3);
    wsrc[i] = W1t + (long)hb*DD + (((lane & 7) ^ (hb & 7))*8);
  }
  // X staging: 1536 f32/macro; thread t, g: idx=g*256+t; row=idx>>6 (0..23), col=idx&63
  const float* xsrc[6];
  int xli[6];
  #pragma unroll
  for (int g = 0; g < 6; ++g){
    int idx = g*256 + t;
    int rowl = idx >> 6, col = idx & 63;
    int grow = (rowl < 8) ? (i0 + rowl) : (j0 + rowl - 8);
    xsrc[g] = X + (long)grow*DD + col;
    xli[g] = rowl*68 + col;
  }

  // prologue: macro 0
  float xr[6];
  #pragma unroll
  for (int i = 0; i < 4; ++i)
    glds16(wsrc[i], WA + (w*32 + i*8)*64);
  #pragma unroll
  for (int g = 0; g < 6; ++g) xr[g] = xsrc[g][0];
  #pragma unroll
  for (int g = 0; g < 6; ++g) XF[xli[g]] = xr[g];
  __syncthreads();

  for (int mk = 0; mk < 20; ++mk){
    const int cb = mk & 1;
    short* WAc = WA + cb*8192;
    float* XFc = XF + cb*1632;
    short* WAn = WA + (cb^1)*8192;
    float* XFn = XF + (cb^1)*1632;
    if (mk < 19){
      #pragma unroll
      for (int i = 0; i < 4; ++i)
        glds16(wsrc[i] + (mk+1)*64, WAn + (w*32 + i*8)*64);
      #pragma unroll
      for (int g = 0; g < 6; ++g) xr[g] = xsrc[g][(mk+1)*64];
    }
    #pragma unroll
    for (int ks = 0; ks < 2; ++ks){
      f32x4 xj0 = *(const f32x4*)&XFc[(8 + l15)*68 + ks*32 + l4*8];
      f32x4 xj1 = *(const f32x4*)&XFc[(8 + l15)*68 + ks*32 + l4*8 + 4];
      bf16x8 a[2];
      #pragma unroll
      for (int m = 0; m < 2; ++m){
        const float* xip = &XFc[(2*w + m)*68 + ks*32 + l4*8];
        f32x4 xi0 = *(const f32x4*)xip;
        f32x4 xi1 = *(const f32x4*)(xip + 4);
        bf16x8 av;
        #pragma unroll
        for (int q = 0; q < 4; ++q){ float dl = xj0[q]-xi0[q]; av[q]   = f2bf_fast(dl*dl); }
        #pragma unroll
        for (int q = 0; q < 4; ++q){ float dl = xj1[q]-xi1[q]; av[4+q] = f2bf_fast(dl*dl); }
        a[m] = av;
      }
      #pragma unroll
      for (int n = 0; n < 8; ++n){
        bf16x8 wf = *(const bf16x8*)&WAc[(n*16 + l15)*64 + (((ks*4 + l4) ^ (l15 & 7))*8)];
        acc[0][n] = __builtin_amdgcn_mfma_f32_16x16x32_bf16(wf, a[0], acc[0][n], 0,0,0);
        acc[1][n] = __builtin_amdgcn_mfma_f32_16x16x32_bf16(wf, a[1], acc[1][n], 0,0,0);
      }
    }
    if (mk < 19){
      #pragma unroll
      for (int g = 0; g < 6; ++g) XFn[xli[g]] = xr[g];
    }
    __syncthreads();
  }

  // ---- TL[pair][h] write (b64 packed, 4 consecutive h) ----
  f32x4 bd1v[8];
  #pragma unroll
  for (int n = 0; n < 8; ++n) bd1v[n] = *(const f32x4*)(bd1 + n*16 + l4*4);
  #pragma unroll
  for (int m = 0; m < 2; ++m){
    int pair = (2*w + m)*16 + l15;
    #pragma unroll
    for (int n = 0; n < 8; ++n){
      bf16x4 pv;
      #pragma unroll
      for (int r = 0; r < 4; ++r){
        float v = acc[m][n][r] + bd1v[n][r];
        v = v > 0.f ? v : 0.f;
        pv[r] = f2bf_fast(v);
      }
      *(bf16x4*)&TL[pair*136 + n*16 + l4*4] = pv;
    }
  }
  __syncthreads();

  // ---- layer 2: wave w owns pairs [w*32, +32) ----
  f32x4 acc2[2][2];
  #pragma unroll
  for (int m2 = 0; m2 < 2; ++m2)
    #pragma unroll
    for (int nn = 0; nn < 2; ++nn) acc2[m2][nn] = (f32x4){0.f,0.f,0.f,0.f};
  #pragma unroll
  for (int hs = 0; hs < 4; ++hs){
    bf16x8 b2[2];
    #pragma unroll
    for (int nn = 0; nn < 2; ++nn)
      b2[nn] = *(const bf16x8*)&W2t[(nn*16 + l15)*HH + hs*32 + l4*8];
    #pragma unroll
    for (int m2 = 0; m2 < 2; ++m2){
      bf16x8 a2 = *(const bf16x8*)&TL[(w*32 + m2*16 + l15)*136 + hs*32 + l4*8];
      #pragma unroll
      for (int nn = 0; nn < 2; ++nn)
        acc2[m2][nn] = __builtin_amdgcn_mfma_f32_16x16x32_bf16(a2, b2[nn], acc2[m2][nn], 0,0,0);
    }
  }
  // OT[pair][30] f32
  #pragma unroll
  for (int m2 = 0; m2 < 2; ++m2){
    #pragma unroll
    for (int nn = 0; nn < 2; ++nn){
      int cc = nn*16 + l15;
      if (cc < 30){
        float b2v = bd2[cc];
        #pragma unroll
        for (int r = 0; r < 4; ++r)
          OT[(w*32 + m2*16 + l4*4 + r)*30 + cc] = acc2[m2][nn][r] + b2v;
      }
    }
  }
  __syncthreads();

  // ---- coalesced global writes from OT ----
  {
    // normal tile: 8 rows (gi), each 480 f32 contiguous
    int i = t >> 5;
    int ca = (t & 31)*15;
    long nbase = ((long)(i0 + i)*NN + j0)*30 + ca;
    const float* nsrc = OT + i*480 + ca;
    #pragma unroll
    for (int q = 0; q < 15; ++q) out[nbase + q] = nsrc[q];
    // mirror tile: 16 rows (gj), each 240 f32 contiguous
    int j = t >> 4;
    int s = t & 15;
    int ii = s >> 1;
    int c0 = (s & 1)*15;
    long mbase = ((long)(j0 + j)*NN + i0 + ii)*30 + c0;
    const float* msrc = OT + ii*480 + j*30 + c0;
    #pragma unroll
    for (int q = 0; q < 15; ++q) out[mbase + q] = msrc[q];
  }
}

// ---------------- launch ----------------
extern "C" void kernel_launch(void* const* d_in, const int* in_sizes, int n_in,
                              void* d_out, int out_size, void* d_ws, size_t ws_size,
                              hipStream_t stream){
  const float* lm   = (const float*)d_in[0];
  const float* nf   = (const float*)d_in[1];
  const float* ef   = (const float*)d_in[2];
  const int*   src  = (const int*)d_in[3];
  const int*   dst  = (const int*)d_in[4];
  const int*   midx = (const int*)d_in[5];
  const float* Wg0  = (const float*)d_in[6];
  const float* bg0  = (const float*)d_in[7];
  const float* Wg1  = (const float*)d_in[8];
  const float* bg1  = (const float*)d_in[9];
  const float* Wd1  = (const float*)d_in[10];
  const float* bd1  = (const float*)d_in[11];
  const float* Wd2  = (const float*)d_in[12];
  const float* bd2  = (const float*)d_in[13];
  const float* Wm1  = (const float*)d_in[14];
  const float* bm1  = (const float*)d_in[15];
  const float* Wm2  = (const float*)d_in[16];
  const float* bm2  = (const float*)d_in[17];
  float* dis = (float*)d_out;

  char* ws = (char*)d_ws;
  size_t off = 0;
  auto alloc = [&](size_t bytes)->void*{
    void* p = ws + off; off += (bytes + 255) & ~(size_t)255; return p;
  };
  float* x0   = (float*)alloc((size_t)NN*DD*4);
  float* yb   = (float*)alloc((size_t)NN*DD*4);
  float* hb   = (float*)alloc((size_t)NN*DD*4);
  float* ew   = (float*)alloc((size_t)EE*4);
  int*   offs = (int*)alloc((NN+1)*4);
  int*   sorted = (int*)alloc(EE*4);
  short* WtAh = (short*)alloc((size_t)DD*DD*2);
  short* WtAl = (short*)alloc((size_t)DD*DD*2);
  short* W1t  = (short*)alloc((size_t)HH*DD*2);
  short* W2t  = (short*)alloc((size_t)32*HH*2);
  float* P    = (float*)alloc((size_t)4*NN*DD*4);

  k_prep<<<1402,512,0,stream>>>(lm, nf, x0, dst, ef, offs, sorted, ew,
                                Wd1, W1t, Wd2, W2t, Wg0, WtAh, WtAl);

  k_agg<<<dim3(384,5),256,0,stream>>>(x0, ew, src, offs, sorted, yb);
  k_gin_gemm<<<dim3(3,10,4),256,0,stream>>>(yb, WtAh, WtAl, P);
  k_red_t<<<880,256,0,stream>>>(P, bg0, nullptr, hb, Wg1, WtAh, WtAl);

  k_agg<<<dim3(384,5),256,0,stream>>>(hb, ew, src, offs, sorted, yb);
  k_gin_gemm<<<dim3(3,10,4),256,0,stream>>>(yb, WtAh, WtAl, P);
  k_red_t<<<480,256,0,stream>>>(P, bg1, x0, hb, nullptr, nullptr, nullptr);

  k_dis<<<664,256,0,stream>>>(hb, W1t, bd1, W2t, bd2, dis,
                              midx, Wm1, bm1, Wm2, bm2);
}